// Round 1
// baseline (2440.383 us; speedup 1.0000x reference)
//
#include <hip/hip_runtime.h>
#include <hip/hip_bf16.h>
#include <cstdint>
#include <cstddef>

// Problem constants
#define Bc 16
#define Lc 1024
#define DMc 512
#define Hc 8
#define DKc 64
#define DVc 64
#define DHc 2048

// ---------------------------------------------------------------------------
// Generic tiled f32 GEMM: C[M,N] = A[M,K] @ W[K,N] + bias[N], optional relu.
// 64x64 tile, BK=16, 256 threads, 4x4 per-thread microtile.
// M,N multiples of 64; K multiple of 16; N,K multiples of 4 (float4 loads).
// ---------------------------------------------------------------------------
__global__ __launch_bounds__(256) void gemm_bias(
    const float* __restrict__ A, const float* __restrict__ W,
    const float* __restrict__ bias, float* __restrict__ C,
    int M, int N, int K, int relu)
{
    __shared__ float As[16][64];   // [k][m]
    __shared__ float Bs[16][64];   // [k][n]
    const int tid = threadIdx.x;
    const int tx = tid & 15;       // n direction
    const int ty = tid >> 4;       // m direction
    const int m0 = blockIdx.y * 64;
    const int n0 = blockIdx.x * 64;

    const int ar = tid >> 2;          // 0..63 row in A tile
    const int ac = (tid & 3) * 4;     // 0,4,8,12
    const int br = tid >> 4;          // 0..15 row in B tile
    const int bc = (tid & 15) * 4;    // 0..60

    float acc[4][4] = {};

    for (int k0 = 0; k0 < K; k0 += 16) {
        float4 av = *reinterpret_cast<const float4*>(&A[(size_t)(m0 + ar) * K + k0 + ac]);
        float4 bv = *reinterpret_cast<const float4*>(&W[(size_t)(k0 + br) * N + n0 + bc]);
        As[ac + 0][ar] = av.x;
        As[ac + 1][ar] = av.y;
        As[ac + 2][ar] = av.z;
        As[ac + 3][ar] = av.w;
        *reinterpret_cast<float4*>(&Bs[br][bc]) = bv;
        __syncthreads();
        #pragma unroll
        for (int kk = 0; kk < 16; ++kk) {
            float a[4], b[4];
            #pragma unroll
            for (int i = 0; i < 4; ++i) a[i] = As[kk][ty * 4 + i];
            #pragma unroll
            for (int j = 0; j < 4; ++j) b[j] = Bs[kk][tx * 4 + j];
            #pragma unroll
            for (int i = 0; i < 4; ++i)
                #pragma unroll
                for (int j = 0; j < 4; ++j)
                    acc[i][j] += a[i] * b[j];
        }
        __syncthreads();
    }

    #pragma unroll
    for (int i = 0; i < 4; ++i) {
        int row = m0 + ty * 4 + i;
        #pragma unroll
        for (int j = 0; j < 4; ++j) {
            int col = n0 + tx * 4 + j;
            float v = acc[i][j] + bias[col];
            if (relu) v = fmaxf(v, 0.0f);
            C[(size_t)row * N + col] = v;
        }
    }
}

// ---------------------------------------------------------------------------
// M[b,h,l] = max_s dot(Q[b,h,l,:], K[b,h,idx[l,s],:]) - mean_s(...)
// One wave (64 lanes) per (b,h,l); lane = d.
// Q,K stored as (B, L, H, 64) row-major (GEMM output layout).
// ---------------------------------------------------------------------------
__global__ __launch_bounds__(256) void compute_M_kernel(
    const float* __restrict__ Q, const float* __restrict__ Kb,
    const int* __restrict__ idx, float* __restrict__ Mout, int u)
{
    int wave = (blockIdx.x * 256 + threadIdx.x) >> 6;  // 0 .. B*H*L-1
    int lane = threadIdx.x & 63;
    int l = wave & (Lc - 1);
    int bh = wave >> 10;
    int h = bh & (Hc - 1);
    int b = bh >> 3;

    float q = Q[((size_t)(b * Lc + l) * Hc + h) * 64 + lane];
    float mx = -INFINITY;
    float sum = 0.0f;
    for (int s = 0; s < u; ++s) {
        int kl = idx[l * u + s];
        float kv = Kb[((size_t)(b * Lc + kl) * Hc + h) * 64 + lane];
        float p = q * kv;
        #pragma unroll
        for (int off = 32; off; off >>= 1) p += __shfl_xor(p, off, 64);
        mx = fmaxf(mx, p);
        sum += p;
    }
    if (lane == 0) Mout[wave] = mx - sum / (float)u;
}

// ---------------------------------------------------------------------------
// Top-u selection per (b,h) row of M (length L). Also builds rowmap[b,h,l] =
// j if l is the j-th selected query else -1. Tie-break: lowest index.
// One block (256 threads) per (b,h).
// ---------------------------------------------------------------------------
__global__ __launch_bounds__(256) void topk_kernel(
    const float* __restrict__ Mvals, int* __restrict__ Mtop,
    int* __restrict__ rowmap, int u)
{
    int bh = blockIdx.x;
    __shared__ float vals[Lc];
    __shared__ float rv[256];
    __shared__ int   ri[256];
    int t = threadIdx.x;
    for (int i = t; i < Lc; i += 256) {
        vals[i] = Mvals[(size_t)bh * Lc + i];
        rowmap[(size_t)bh * Lc + i] = -1;
    }
    __syncthreads();
    for (int j = 0; j < u; ++j) {
        float bv = -INFINITY; int bi = Lc;
        for (int i = t; i < Lc; i += 256) {
            float v = vals[i];
            if (v > bv) { bv = v; bi = i; }
        }
        rv[t] = bv; ri[t] = bi;
        __syncthreads();
        for (int s = 128; s; s >>= 1) {
            if (t < s) {
                float v2 = rv[t + s]; int i2 = ri[t + s];
                if (v2 > rv[t] || (v2 == rv[t] && i2 < ri[t])) { rv[t] = v2; ri[t] = i2; }
            }
            __syncthreads();
        }
        if (t == 0) {
            int bidx = ri[0];
            Mtop[bh * u + j] = bidx;
            rowmap[(size_t)bh * Lc + bidx] = j;
            vals[bidx] = -INFINITY;
        }
        __syncthreads();
    }
}

// ---------------------------------------------------------------------------
// attn[b,h,j,:] = softmax_l( dot(Q[b,h,qpos,:], K[b,h,l,:]) / 8 )
// One block (256 threads) per (b,h,j). Each thread does 4 rows of K.
// ---------------------------------------------------------------------------
__global__ __launch_bounds__(256) void attn_scores_kernel(
    const float* __restrict__ Q, const float* __restrict__ Kb,
    const int* __restrict__ Mtop, float* __restrict__ attn, int u)
{
    int task = blockIdx.x;          // 0..B*H*u-1
    int j = task % u; int bh = task / u;
    int h = bh & (Hc - 1); int b = bh >> 3;
    int qpos = Mtop[bh * u + j];

    __shared__ float qrow[64];
    __shared__ float red[256];
    int t = threadIdx.x;
    if (t < 64) qrow[t] = Q[((size_t)(b * Lc + qpos) * Hc + h) * 64 + t];
    __syncthreads();

    float myv[4];
    float lmax = -INFINITY;
    #pragma unroll
    for (int c = 0; c < 4; ++c) {
        int l = t + c * 256;
        const float4* kr = reinterpret_cast<const float4*>(
            &Kb[((size_t)(b * Lc + l) * Hc + h) * 64]);
        float dot = 0.0f;
        #pragma unroll
        for (int d4 = 0; d4 < 16; ++d4) {
            float4 kv = kr[d4];
            dot += qrow[d4*4+0]*kv.x + qrow[d4*4+1]*kv.y + qrow[d4*4+2]*kv.z + qrow[d4*4+3]*kv.w;
        }
        myv[c] = dot * 0.125f;
        lmax = fmaxf(lmax, myv[c]);
    }
    red[t] = lmax; __syncthreads();
    for (int s = 128; s; s >>= 1) { if (t < s) red[t] = fmaxf(red[t], red[t + s]); __syncthreads(); }
    float m = red[0];
    __syncthreads();
    float lsum = 0.0f;
    #pragma unroll
    for (int c = 0; c < 4; ++c) { myv[c] = expf(myv[c] - m); lsum += myv[c]; }
    red[t] = lsum; __syncthreads();
    for (int s = 128; s; s >>= 1) { if (t < s) red[t] += red[t + s]; __syncthreads(); }
    float inv = 1.0f / red[0];
    #pragma unroll
    for (int c = 0; c < 4; ++c)
        attn[(size_t)task * Lc + t + c * 256] = myv[c] * inv;
}

// ---------------------------------------------------------------------------
// Vmean[b,h,d] = mean over l of V[b,l,h,d]. One block per (b,h).
// ---------------------------------------------------------------------------
__global__ __launch_bounds__(256) void vmean_kernel(
    const float* __restrict__ V, float* __restrict__ Vm)
{
    int bh = blockIdx.x; int h = bh & (Hc - 1); int b = bh >> 3;
    int t = threadIdx.x; int d = t & 63; int part = t >> 6;
    float s = 0.0f;
    for (int l = part; l < Lc; l += 4)
        s += V[((size_t)(b * Lc + l) * Hc + h) * 64 + d];
    __shared__ float red[256];
    red[t] = s; __syncthreads();
    if (t < 64) {
        float tot = red[t] + red[t + 64] + red[t + 128] + red[t + 192];
        Vm[bh * 64 + t] = tot * (1.0f / Lc);
    }
}

// ctx[b,l,h,d] = Vmean[b,h,d] for all rows.
__global__ __launch_bounds__(256) void ctx_fill_kernel(
    float* __restrict__ ctx, const float* __restrict__ Vm)
{
    size_t i = (size_t)blockIdx.x * 256 + threadIdx.x;  // over B*L*H*64
    int d = (int)(i & 63);
    int h = (int)((i >> 6) & 7);
    size_t bl = i >> 9;
    int b = (int)(bl >> 10);
    ctx[i] = Vm[(b * 8 + h) * 64 + d];
}

// ctx[b, qpos, h, :] = attn[b,h,j,:] @ V[b,h,:,:]. One block per (b,h,j).
__global__ __launch_bounds__(256) void ctx_scatter_kernel(
    const float* __restrict__ attn, const float* __restrict__ V,
    const int* __restrict__ Mtop, float* __restrict__ ctx, int u)
{
    int task = blockIdx.x;
    int j = task % u; int bh = task / u;
    int h = bh & (Hc - 1); int b = bh >> 3;
    int qpos = Mtop[bh * u + j];
    int t = threadIdx.x; int d = t & 63; int part = t >> 6;
    float s = 0.0f;
    for (int l = part; l < Lc; l += 4)
        s += attn[(size_t)task * Lc + l] * V[((size_t)(b * Lc + l) * Hc + h) * 64 + d];
    __shared__ float red[256];
    red[t] = s; __syncthreads();
    if (t < 64) {
        float tot = red[t] + red[t + 64] + red[t + 128] + red[t + 192];
        ctx[((size_t)(b * Lc + qpos) * Hc + h) * 64 + t] = tot;
    }
}

// y[row,:] = LN(a[row,:] + b[row,:]) * g + beta  over DM=512. Block per row.
__global__ __launch_bounds__(256) void ln_residual_kernel(
    const float* __restrict__ a, const float* __restrict__ bsrc,
    const float* __restrict__ g, const float* __restrict__ beta,
    float* __restrict__ y)
{
    int row = blockIdx.x;
    int t = threadIdx.x;
    const float* ar = a + (size_t)row * DMc;
    const float* br = bsrc + (size_t)row * DMc;
    float v0 = ar[t] + br[t];
    float v1 = ar[t + 256] + br[t + 256];
    __shared__ float red[256];
    red[t] = v0 + v1; __syncthreads();
    for (int s = 128; s; s >>= 1) { if (t < s) red[t] += red[t + s]; __syncthreads(); }
    float mean = red[0] * (1.0f / DMc);
    __syncthreads();
    float d0 = v0 - mean, d1 = v1 - mean;
    red[t] = d0 * d0 + d1 * d1; __syncthreads();
    for (int s = 128; s; s >>= 1) { if (t < s) red[t] += red[t + s]; __syncthreads(); }
    float inv = rsqrtf(red[0] * (1.0f / DMc) + 1e-5f);
    y[(size_t)row * DMc + t]       = g[t] * d0 * inv + beta[t];
    y[(size_t)row * DMc + t + 256] = g[t + 256] * d1 * inv + beta[t + 256];
}

// score[b,h,l,:] = attn row if l selected else 1/L. One block per (b,h,l).
__global__ __launch_bounds__(256) void score_write_kernel(
    const float* __restrict__ attn, const int* __restrict__ rowmap,
    float* __restrict__ score, int u)
{
    size_t row = blockIdx.x;          // 0 .. B*H*L-1
    int bh = (int)(row >> 10);
    int j = rowmap[row];
    int t = threadIdx.x;
    float4* dst = reinterpret_cast<float4*>(score + row * Lc);
    if (j >= 0) {
        const float4* src = reinterpret_cast<const float4*>(attn + ((size_t)bh * u + j) * Lc);
        dst[t] = src[t];
    } else {
        const float iv = 1.0f / (float)Lc;
        dst[t] = make_float4(iv, iv, iv, iv);
    }
}

// ---------------------------------------------------------------------------
extern "C" void kernel_launch(void* const* d_in, const int* in_sizes, int n_in,
                              void* d_out, int out_size, void* d_ws, size_t ws_size,
                              hipStream_t stream)
{
    const float* x     = (const float*)d_in[0];
    const float* Wq    = (const float*)d_in[1];
    const float* bq    = (const float*)d_in[2];
    const float* Wk    = (const float*)d_in[3];
    const float* bk    = (const float*)d_in[4];
    const float* Wv    = (const float*)d_in[5];
    const float* bv    = (const float*)d_in[6];
    const float* Wo    = (const float*)d_in[7];
    const float* bo    = (const float*)d_in[8];
    const float* g1    = (const float*)d_in[9];
    const float* beta1 = (const float*)d_in[10];
    const float* W1    = (const float*)d_in[11];
    const float* bf1   = (const float*)d_in[12];
    const float* W2    = (const float*)d_in[13];
    const float* bf2   = (const float*)d_in[14];
    const float* g2    = (const float*)d_in[15];
    const float* beta2 = (const float*)d_in[16];
    const int* index_sample = (const int*)d_in[17];
    const int u = in_sizes[17] / Lc;   // 35

    const size_t NTOK = (size_t)Bc * Lc;            // 16384
    const size_t QKV_SZ = NTOK * DMc;               // 8,388,608
    const size_t ATTN_SZ = (size_t)Bc * Hc * u * Lc;
    const size_t HID_SZ = NTOK * DHc;               // 33,554,432

    float* ws = (float*)d_ws;
    float* Q      = ws;               // also reused as ctx
    float* Kb     = Q + QKV_SZ;       // also reused as x1
    float* V      = Kb + QKV_SZ;      // also reused as out/ffn temp
    float* attn   = V + QKV_SZ;
    float* hidden = attn + ATTN_SZ;
    float* Mbuf   = hidden + HID_SZ;                 // B*H*L
    float* Vm     = Mbuf + (size_t)Bc * Hc * Lc;     // B*H*64
    int*   rowmap = (int*)(Vm + (size_t)Bc * Hc * 64);
    int*   Mtop   = rowmap + (size_t)Bc * Hc * Lc;

    float* x2_out    = (float*)d_out;
    float* score_out = x2_out + QKV_SZ;

    dim3 blk(256);
    dim3 g512((DMc) / 64, NTOK / 64);     // N=512 GEMMs
    dim3 g2048((DHc) / 64, NTOK / 64);    // N=2048 GEMM

    // QKV projections
    gemm_bias<<<g512, blk, 0, stream>>>(x, Wq, bq, Q, (int)NTOK, DMc, DMc, 0);
    gemm_bias<<<g512, blk, 0, stream>>>(x, Wk, bk, Kb, (int)NTOK, DMc, DMc, 0);
    gemm_bias<<<g512, blk, 0, stream>>>(x, Wv, bv, V, (int)NTOK, DMc, DMc, 0);

    // sparsity measurement M
    compute_M_kernel<<<(Bc * Hc * Lc) / 4, blk, 0, stream>>>(Q, Kb, index_sample, Mbuf, u);

    // top-u per (b,h) + rowmap
    topk_kernel<<<Bc * Hc, blk, 0, stream>>>(Mbuf, Mtop, rowmap, u);

    // reduced-Q attention scores + softmax
    attn_scores_kernel<<<Bc * Hc * u, blk, 0, stream>>>(Q, Kb, Mtop, attn, u);

    // context: V mean broadcast, then scatter attn @ V rows (ctx reuses Q)
    vmean_kernel<<<Bc * Hc, blk, 0, stream>>>(V, Vm);
    ctx_fill_kernel<<<(int)(QKV_SZ / 256), blk, 0, stream>>>(Q, Vm);
    ctx_scatter_kernel<<<Bc * Hc * u, blk, 0, stream>>>(attn, V, Mtop, Q, u);

    // output projection (into V region) + LN1 -> x1 (Kb region)
    gemm_bias<<<g512, blk, 0, stream>>>(Q, Wo, bo, V, (int)NTOK, DMc, DMc, 0);
    ln_residual_kernel<<<(int)NTOK, blk, 0, stream>>>(V, x, g1, beta1, Kb);

    // FFN
    gemm_bias<<<g2048, blk, 0, stream>>>(Kb, W1, bf1, hidden, (int)NTOK, DHc, DMc, 1);
    gemm_bias<<<g512, blk, 0, stream>>>(hidden, W2, bf2, V, (int)NTOK, DMc, DHc, 0);
    ln_residual_kernel<<<(int)NTOK, blk, 0, stream>>>(V, Kb, g2, beta2, x2_out);

    // score output tensor
    score_write_kernel<<<Bc * Hc * Lc, blk, 0, stream>>>(attn, rowmap, score_out, u);
}

// Round 2
// 1267.095 us; speedup vs baseline: 1.9260x; 1.9260x over previous
//
#include <hip/hip_runtime.h>
#include <cstdint>
#include <cstddef>

// Problem constants
#define Bc 16
#define Lc 1024
#define DMc 512
#define Hc 8
#define DHc 2048

typedef __attribute__((ext_vector_type(8))) short bf16x8;
typedef __attribute__((ext_vector_type(4))) float f32x4;

__device__ __forceinline__ ushort f2bf(float f) {
    union { float f; uint32_t u; } v; v.f = f;
    uint32_t r = v.u + 0x7FFF + ((v.u >> 16) & 1);   // round-to-nearest-even
    return (ushort)(r >> 16);
}

// async global->LDS, 16 bytes per lane; LDS dest must be wave-uniform base
__device__ __forceinline__ void glds16(const ushort* g, ushort* l) {
    __builtin_amdgcn_global_load_lds(
        (__attribute__((address_space(1))) void*)(void*)const_cast<ushort*>(g),
        (__attribute__((address_space(3))) void*)l, 16, 0, 0);
}

// ---------------------------------------------------------------------------
// bf16 MFMA GEMM (m97 structure): C[M,N] = A[M,K] @ Bt[N,K]^T + bias.
// 128x128 tile, BK=32, 256 threads (4 waves, 2x2), 4x4 16x16x32 frags/wave.
// M%128==0, N%128==0, K%32==0.
// ---------------------------------------------------------------------------
template<int RELU, int OUTBF>
__global__ __launch_bounds__(256) void gemm_mfma(
    const ushort* __restrict__ A, const ushort* __restrict__ Bt,
    const float* __restrict__ bias, void* __restrict__ Cout,
    int M, int N, int K)
{
    __shared__ ushort As[128 * 32];
    __shared__ ushort Bs[128 * 32];
    const int tid = threadIdx.x;
    const int lane = tid & 63;
    const int wave = tid >> 6;
    const int wr = wave >> 1, wc = wave & 1;
    const int m0 = blockIdx.y * 128, n0 = blockIdx.x * 128;
    const int lrow = lane & 15;
    const int lk = (lane >> 4) * 8;

    f32x4 zero = {0.f, 0.f, 0.f, 0.f};
    f32x4 acc[4][4];
    #pragma unroll
    for (int m = 0; m < 4; ++m)
        #pragma unroll
        for (int n = 0; n < 4; ++n) acc[m][n] = zero;

    const int srow = tid >> 2;            // 0..63
    const int skc = (tid & 3) * 8;        // 0,8,16,24
    const int ldsbase = (tid & 192) * 8;  // wave * 512 elements

    for (int k0 = 0; k0 < K; k0 += 32) {
        const ushort* ga0 = A  + (size_t)(m0 + srow) * K + k0 + skc;
        const ushort* ga1 = A  + (size_t)(m0 + 64 + srow) * K + k0 + skc;
        const ushort* gb0 = Bt + (size_t)(n0 + srow) * K + k0 + skc;
        const ushort* gb1 = Bt + (size_t)(n0 + 64 + srow) * K + k0 + skc;
        glds16(ga0, &As[ldsbase]);
        glds16(ga1, &As[2048 + ldsbase]);
        glds16(gb0, &Bs[ldsbase]);
        glds16(gb1, &Bs[2048 + ldsbase]);
        __syncthreads();

        bf16x8 af[4], bv[4];
        #pragma unroll
        for (int m = 0; m < 4; ++m)
            af[m] = *reinterpret_cast<const bf16x8*>(&As[(wr * 64 + m * 16 + lrow) * 32 + lk]);
        #pragma unroll
        for (int n = 0; n < 4; ++n)
            bv[n] = *reinterpret_cast<const bf16x8*>(&Bs[(wc * 64 + n * 16 + lrow) * 32 + lk]);
        #pragma unroll
        for (int m = 0; m < 4; ++m)
            #pragma unroll
            for (int n = 0; n < 4; ++n)
                acc[m][n] = __builtin_amdgcn_mfma_f32_16x16x32_bf16(af[m], bv[n], acc[m][n], 0, 0, 0);
        __syncthreads();
    }

    #pragma unroll
    for (int n = 0; n < 4; ++n) {
        int col = n0 + wc * 64 + n * 16 + lrow;
        float bval = bias[col];
        #pragma unroll
        for (int m = 0; m < 4; ++m) {
            #pragma unroll
            for (int j = 0; j < 4; ++j) {
                int row = m0 + wr * 64 + m * 16 + (lane >> 4) * 4 + j;
                float v = acc[m][n][j] + bval;
                if (RELU) v = fmaxf(v, 0.0f);
                if (OUTBF) ((ushort*)Cout)[(size_t)row * N + col] = f2bf(v);
                else       ((float*)Cout)[(size_t)row * N + col] = v;
            }
        }
    }
}

// f32 [K][N] -> bf16 [N][K] (transpose + convert), 32x32 tiles
__global__ __launch_bounds__(256) void transpose_bf16(
    const float* __restrict__ in, ushort* __restrict__ out, int K, int N)
{
    __shared__ float t[32][33];
    int n0 = blockIdx.x * 32, k0 = blockIdx.y * 32;
    int tx = threadIdx.x & 31, ty = threadIdx.x >> 5;  // ty 0..7
    #pragma unroll
    for (int dy = 0; dy < 32; dy += 8)
        t[ty + dy][tx] = in[(size_t)(k0 + ty + dy) * N + n0 + tx];
    __syncthreads();
    #pragma unroll
    for (int dy = 0; dy < 32; dy += 8)
        out[(size_t)(n0 + ty + dy) * K + k0 + tx] = f2bf(t[tx][ty + dy]);
}

// flat f32 -> bf16, 4 elems/thread
__global__ __launch_bounds__(256) void conv_bf16x4(
    const float* __restrict__ in, ushort* __restrict__ out, int n4)
{
    int i = blockIdx.x * 256 + threadIdx.x;
    if (i >= n4) return;
    float4 v = reinterpret_cast<const float4*>(in)[i];
    uint32_t lo = (uint32_t)f2bf(v.x) | ((uint32_t)f2bf(v.y) << 16);
    uint32_t hi = (uint32_t)f2bf(v.z) | ((uint32_t)f2bf(v.w) << 16);
    reinterpret_cast<uint2*>(out)[i] = make_uint2(lo, hi);
}

// ---------------------------------------------------------------------------
// M[b,h,l] = max_s dot(Q[b,h,l,:],K[...]) - mean_s. One wave per (b,h,l).
// ---------------------------------------------------------------------------
__global__ __launch_bounds__(256) void compute_M_kernel(
    const float* __restrict__ Q, const float* __restrict__ Kb,
    const int* __restrict__ idx, float* __restrict__ Mout, int u)
{
    int wave = (blockIdx.x * 256 + threadIdx.x) >> 6;
    int lane = threadIdx.x & 63;
    int l = wave & (Lc - 1);
    int bh = wave >> 10;
    int h = bh & (Hc - 1);
    int b = bh >> 3;

    float q = Q[((size_t)(b * Lc + l) * Hc + h) * 64 + lane];
    float mx = -INFINITY;
    float sum = 0.0f;
    for (int s = 0; s < u; ++s) {
        int kl = idx[l * u + s];
        float kv = Kb[((size_t)(b * Lc + kl) * Hc + h) * 64 + lane];
        float p = q * kv;
        #pragma unroll
        for (int off = 32; off; off >>= 1) p += __shfl_xor(p, off, 64);
        mx = fmaxf(mx, p);
        sum += p;
    }
    if (lane == 0) Mout[wave] = mx - sum / (float)u;
}

// ---------------------------------------------------------------------------
// Top-u per (b,h); builds rowmap. Tie-break lowest index. Block per (b,h).
// ---------------------------------------------------------------------------
__global__ __launch_bounds__(256) void topk_kernel(
    const float* __restrict__ Mvals, int* __restrict__ Mtop,
    int* __restrict__ rowmap, int u)
{
    int bh = blockIdx.x;
    __shared__ float vals[Lc];
    __shared__ float rv[256];
    __shared__ int   ri[256];
    int t = threadIdx.x;
    for (int i = t; i < Lc; i += 256) {
        vals[i] = Mvals[(size_t)bh * Lc + i];
        rowmap[(size_t)bh * Lc + i] = -1;
    }
    __syncthreads();
    for (int j = 0; j < u; ++j) {
        float bv = -INFINITY; int bi = Lc;
        for (int i = t; i < Lc; i += 256) {
            float v = vals[i];
            if (v > bv) { bv = v; bi = i; }
        }
        rv[t] = bv; ri[t] = bi;
        __syncthreads();
        for (int s = 128; s; s >>= 1) {
            if (t < s) {
                float v2 = rv[t + s]; int i2 = ri[t + s];
                if (v2 > rv[t] || (v2 == rv[t] && i2 < ri[t])) { rv[t] = v2; ri[t] = i2; }
            }
            __syncthreads();
        }
        if (t == 0) {
            int bidx = ri[0];
            Mtop[bh * u + j] = bidx;
            rowmap[(size_t)bh * Lc + bidx] = j;
            vals[bidx] = -INFINITY;
        }
        __syncthreads();
    }
}

// ---------------------------------------------------------------------------
// attn[b,h,j,:] = softmax_l( dot(Q[qpos],K[l]) / 8 ). Block per (b,h,j).
// ---------------------------------------------------------------------------
__global__ __launch_bounds__(256) void attn_scores_kernel(
    const float* __restrict__ Q, const float* __restrict__ Kb,
    const int* __restrict__ Mtop, float* __restrict__ attn, int u)
{
    int task = blockIdx.x;
    int j = task % u; int bh = task / u;
    int h = bh & (Hc - 1); int b = bh >> 3;
    int qpos = Mtop[bh * u + j];

    __shared__ float qrow[64];
    __shared__ float red[256];
    int t = threadIdx.x;
    if (t < 64) qrow[t] = Q[((size_t)(b * Lc + qpos) * Hc + h) * 64 + t];
    __syncthreads();

    float myv[4];
    float lmax = -INFINITY;
    #pragma unroll
    for (int c = 0; c < 4; ++c) {
        int l = t + c * 256;
        const float4* kr = reinterpret_cast<const float4*>(
            &Kb[((size_t)(b * Lc + l) * Hc + h) * 64]);
        float dot = 0.0f;
        #pragma unroll
        for (int d4 = 0; d4 < 16; ++d4) {
            float4 kv = kr[d4];
            dot += qrow[d4*4+0]*kv.x + qrow[d4*4+1]*kv.y + qrow[d4*4+2]*kv.z + qrow[d4*4+3]*kv.w;
        }
        myv[c] = dot * 0.125f;
        lmax = fmaxf(lmax, myv[c]);
    }
    red[t] = lmax; __syncthreads();
    for (int s = 128; s; s >>= 1) { if (t < s) red[t] = fmaxf(red[t], red[t + s]); __syncthreads(); }
    float m = red[0];
    __syncthreads();
    float lsum = 0.0f;
    #pragma unroll
    for (int c = 0; c < 4; ++c) { myv[c] = expf(myv[c] - m); lsum += myv[c]; }
    red[t] = lsum; __syncthreads();
    for (int s = 128; s; s >>= 1) { if (t < s) red[t] += red[t + s]; __syncthreads(); }
    float inv = 1.0f / red[0];
    #pragma unroll
    for (int c = 0; c < 4; ++c)
        attn[(size_t)task * Lc + t + c * 256] = myv[c] * inv;
}

// Vmean[b,h,d] over l. Block per (b,h).
__global__ __launch_bounds__(256) void vmean_kernel(
    const float* __restrict__ V, float* __restrict__ Vm)
{
    int bh = blockIdx.x; int h = bh & (Hc - 1); int b = bh >> 3;
    int t = threadIdx.x; int d = t & 63; int part = t >> 6;
    float s = 0.0f;
    for (int l = part; l < Lc; l += 4)
        s += V[((size_t)(b * Lc + l) * Hc + h) * 64 + d];
    __shared__ float red[256];
    red[t] = s; __syncthreads();
    if (t < 64) {
        float tot = red[t] + red[t + 64] + red[t + 128] + red[t + 192];
        Vm[bh * 64 + t] = tot * (1.0f / Lc);
    }
}

// ctx[b,l,h,d] = bf16(Vmean[b,h,d])
__global__ __launch_bounds__(256) void ctx_fill_bf(
    ushort* __restrict__ ctx, const float* __restrict__ Vm)
{
    size_t i = (size_t)blockIdx.x * 256 + threadIdx.x;
    int d = (int)(i & 63);
    int h = (int)((i >> 6) & 7);
    int b = (int)(i >> 19);
    ctx[i] = f2bf(Vm[(b * 8 + h) * 64 + d]);
}

// ctx[b,qpos,h,:] = bf16( attn[b,h,j,:] @ V[b,h,:,:] ). Block per (b,h,j).
__global__ __launch_bounds__(256) void ctx_scatter_bf(
    const float* __restrict__ attn, const float* __restrict__ V,
    const int* __restrict__ Mtop, ushort* __restrict__ ctx, int u)
{
    int task = blockIdx.x;
    int j = task % u; int bh = task / u;
    int h = bh & (Hc - 1); int b = bh >> 3;
    int qpos = Mtop[bh * u + j];
    int t = threadIdx.x; int d = t & 63; int part = t >> 6;
    float s = 0.0f;
    for (int l = part; l < Lc; l += 4)
        s += attn[(size_t)task * Lc + l] * V[((size_t)(b * Lc + l) * Hc + h) * 64 + d];
    __shared__ float red[256];
    red[t] = s; __syncthreads();
    if (t < 64) {
        float tot = red[t] + red[t + 64] + red[t + 128] + red[t + 192];
        ctx[((size_t)(b * Lc + qpos) * Hc + h) * 64 + t] = f2bf(tot);
    }
}

// y = LN(a+b)*g+beta over DM=512; optional bf16 copy. Block per row.
__global__ __launch_bounds__(256) void ln_residual_kernel(
    const float* __restrict__ a, const float* __restrict__ bsrc,
    const float* __restrict__ g, const float* __restrict__ beta,
    float* __restrict__ y, ushort* __restrict__ ybf)
{
    int row = blockIdx.x;
    int t = threadIdx.x;
    const float* ar = a + (size_t)row * DMc;
    const float* br = bsrc + (size_t)row * DMc;
    float v0 = ar[t] + br[t];
    float v1 = ar[t + 256] + br[t + 256];
    __shared__ float red[256];
    red[t] = v0 + v1; __syncthreads();
    for (int s = 128; s; s >>= 1) { if (t < s) red[t] += red[t + s]; __syncthreads(); }
    float mean = red[0] * (1.0f / DMc);
    __syncthreads();
    float d0 = v0 - mean, d1 = v1 - mean;
    red[t] = d0 * d0 + d1 * d1; __syncthreads();
    for (int s = 128; s; s >>= 1) { if (t < s) red[t] += red[t + s]; __syncthreads(); }
    float inv = rsqrtf(red[0] * (1.0f / DMc) + 1e-5f);
    float o0 = g[t] * d0 * inv + beta[t];
    float o1 = g[t + 256] * d1 * inv + beta[t + 256];
    y[(size_t)row * DMc + t]       = o0;
    y[(size_t)row * DMc + t + 256] = o1;
    if (ybf) {
        ybf[(size_t)row * DMc + t]       = f2bf(o0);
        ybf[(size_t)row * DMc + t + 256] = f2bf(o1);
    }
}

// score[b,h,l,:] = attn row if selected else 1/L. Block per (b,h,l).
__global__ __launch_bounds__(256) void score_write_kernel(
    const float* __restrict__ attn, const int* __restrict__ rowmap,
    float* __restrict__ score, int u)
{
    size_t row = blockIdx.x;
    int bh = (int)(row >> 10);
    int j = rowmap[row];
    int t = threadIdx.x;
    float4* dst = reinterpret_cast<float4*>(score + row * Lc);
    if (j >= 0) {
        const float4* src = reinterpret_cast<const float4*>(attn + ((size_t)bh * u + j) * Lc);
        dst[t] = src[t];
    } else {
        const float iv = 1.0f / (float)Lc;
        dst[t] = make_float4(iv, iv, iv, iv);
    }
}

// ---------------------------------------------------------------------------
extern "C" void kernel_launch(void* const* d_in, const int* in_sizes, int n_in,
                              void* d_out, int out_size, void* d_ws, size_t ws_size,
                              hipStream_t stream)
{
    const float* x     = (const float*)d_in[0];
    const float* Wq    = (const float*)d_in[1];
    const float* bq    = (const float*)d_in[2];
    const float* Wk    = (const float*)d_in[3];
    const float* bk    = (const float*)d_in[4];
    const float* Wv    = (const float*)d_in[5];
    const float* bv    = (const float*)d_in[6];
    const float* Wo    = (const float*)d_in[7];
    const float* bo    = (const float*)d_in[8];
    const float* g1    = (const float*)d_in[9];
    const float* beta1 = (const float*)d_in[10];
    const float* W1    = (const float*)d_in[11];
    const float* bf1   = (const float*)d_in[12];
    const float* W2    = (const float*)d_in[13];
    const float* bf2   = (const float*)d_in[14];
    const float* g2    = (const float*)d_in[15];
    const float* beta2 = (const float*)d_in[16];
    const int* index_sample = (const int*)d_in[17];
    const int u = in_sizes[17] / Lc;   // 35

    const size_t NTOK = (size_t)Bc * Lc;            // 16384
    const size_t QKV_SZ = NTOK * DMc;               // 8,388,608
    const size_t ATTN_SZ = (size_t)Bc * Hc * u * Lc;
    const size_t HID_SZ = NTOK * DHc;               // 33,554,432

    char* p = (char*)d_ws;
    auto alloc = [&](size_t bytes) { char* r = p; p += (bytes + 255) & ~(size_t)255; return r; };
    float*  Q      = (float*) alloc(QKV_SZ * 4);
    float*  Kf     = (float*) alloc(QKV_SZ * 4);   // K, later x1 (f32)
    float*  V      = (float*) alloc(QKV_SZ * 4);   // V, later proj/ffn out
    float*  attn   = (float*) alloc(ATTN_SZ * 4);
    ushort* hidden = (ushort*)alloc(HID_SZ * 2);
    ushort* xbf    = (ushort*)alloc(QKV_SZ * 2);
    ushort* ctxbf  = (ushort*)alloc(QKV_SZ * 2);
    ushort* x1bf   = (ushort*)alloc(QKV_SZ * 2);
    ushort* Wqt    = (ushort*)alloc((size_t)512 * 512 * 2);
    ushort* Wkt    = (ushort*)alloc((size_t)512 * 512 * 2);
    ushort* Wvt    = (ushort*)alloc((size_t)512 * 512 * 2);
    ushort* Wot    = (ushort*)alloc((size_t)512 * 512 * 2);
    ushort* W1t    = (ushort*)alloc((size_t)512 * 2048 * 2);
    ushort* W2t    = (ushort*)alloc((size_t)512 * 2048 * 2);
    float*  Mbuf   = (float*) alloc((size_t)Bc * Hc * Lc * 4);
    float*  Vm     = (float*) alloc((size_t)Bc * Hc * 64 * 4);
    int*    rowmap = (int*)   alloc((size_t)Bc * Hc * Lc * 4);
    int*    Mtop   = (int*)   alloc((size_t)Bc * Hc * 64 * 4);

    float* x2_out    = (float*)d_out;
    float* score_out = x2_out + QKV_SZ;

    dim3 blk(256);

    // bf16 conversions
    conv_bf16x4<<<(int)(QKV_SZ / 4 / 256), blk, 0, stream>>>(x, xbf, (int)(QKV_SZ / 4));
    transpose_bf16<<<dim3(16, 16), blk, 0, stream>>>(Wq, Wqt, 512, 512);
    transpose_bf16<<<dim3(16, 16), blk, 0, stream>>>(Wk, Wkt, 512, 512);
    transpose_bf16<<<dim3(16, 16), blk, 0, stream>>>(Wv, Wvt, 512, 512);
    transpose_bf16<<<dim3(16, 16), blk, 0, stream>>>(Wo, Wot, 512, 512);
    transpose_bf16<<<dim3(64, 16), blk, 0, stream>>>(W1, W1t, 512, 2048);
    transpose_bf16<<<dim3(16, 64), blk, 0, stream>>>(W2, W2t, 2048, 512);

    // QKV projections (f32 out)
    gemm_mfma<0,0><<<dim3(4, 128), blk, 0, stream>>>(xbf, Wqt, bq, Q,  (int)NTOK, 512, 512);
    gemm_mfma<0,0><<<dim3(4, 128), blk, 0, stream>>>(xbf, Wkt, bk, Kf, (int)NTOK, 512, 512);
    gemm_mfma<0,0><<<dim3(4, 128), blk, 0, stream>>>(xbf, Wvt, bv, V,  (int)NTOK, 512, 512);

    // ProbSparse selection
    compute_M_kernel<<<(Bc * Hc * Lc) / 4, blk, 0, stream>>>(Q, Kf, index_sample, Mbuf, u);
    topk_kernel<<<Bc * Hc, blk, 0, stream>>>(Mbuf, Mtop, rowmap, u);
    attn_scores_kernel<<<Bc * Hc * u, blk, 0, stream>>>(Q, Kf, Mtop, attn, u);

    // context (bf16)
    vmean_kernel<<<Bc * Hc, blk, 0, stream>>>(V, Vm);
    ctx_fill_bf<<<(int)(QKV_SZ / 256), blk, 0, stream>>>(ctxbf, Vm);
    ctx_scatter_bf<<<Bc * Hc * u, blk, 0, stream>>>(attn, V, Mtop, ctxbf, u);

    // output projection + LN1 (x1 -> Kf f32 + x1bf)
    gemm_mfma<0,0><<<dim3(4, 128), blk, 0, stream>>>(ctxbf, Wot, bo, V, (int)NTOK, 512, 512);
    ln_residual_kernel<<<(int)NTOK, blk, 0, stream>>>(V, x, g1, beta1, Kf, x1bf);

    // FFN: GEMM1 writes bf16 hidden directly (relu), GEMM2 f32
    gemm_mfma<1,1><<<dim3(16, 128), blk, 0, stream>>>(x1bf, W1t, bf1, hidden, (int)NTOK, 2048, 512);
    gemm_mfma<0,0><<<dim3(4, 128), blk, 0, stream>>>(hidden, W2t, bf2, V, (int)NTOK, 512, 2048);
    ln_residual_kernel<<<(int)NTOK, blk, 0, stream>>>(V, Kf, g2, beta2, x2_out, nullptr);

    // score output
    score_write_kernel<<<Bc * Hc * Lc, blk, 0, stream>>>(attn, rowmap, score_out, u);
}

// Round 3
// 923.735 us; speedup vs baseline: 2.6419x; 1.3717x over previous
//
#include <hip/hip_runtime.h>
#include <cstdint>
#include <cstddef>

// Problem constants
#define Bc 16
#define Lc 1024
#define DMc 512
#define Hc 8
#define DHc 2048
#define Uc 35        // FACTOR*ceil(ln(L)) = 5*7, fixed by problem setup

typedef __attribute__((ext_vector_type(8))) short bf16x8;
typedef __attribute__((ext_vector_type(4))) float f32x4;

__device__ __forceinline__ ushort f2bf(float f) {
    union { float f; uint32_t u; } v; v.f = f;
    uint32_t r = v.u + 0x7FFF + ((v.u >> 16) & 1);   // round-to-nearest-even
    return (ushort)(r >> 16);
}

// async global->LDS, 16 bytes per lane; LDS dest must be wave-uniform base
__device__ __forceinline__ void glds16(const ushort* g, ushort* l) {
    __builtin_amdgcn_global_load_lds(
        (__attribute__((address_space(1))) void*)(void*)const_cast<ushort*>(g),
        (__attribute__((address_space(3))) void*)l, 16, 0, 0);
}

// ---------------------------------------------------------------------------
// bf16 MFMA GEMM (m97 structure): C[M,N] = A[M,K] @ Bt[N,K]^T + bias.
// 128x128 tile, BK=32, 256 threads (4 waves, 2x2), 4x4 16x16x32 frags/wave.
// ---------------------------------------------------------------------------
template<int RELU, int OUTBF>
__global__ __launch_bounds__(256) void gemm_mfma(
    const ushort* __restrict__ A, const ushort* __restrict__ Bt,
    const float* __restrict__ bias, void* __restrict__ Cout,
    int M, int N, int K)
{
    __shared__ ushort As[128 * 32];
    __shared__ ushort Bs[128 * 32];
    const int tid = threadIdx.x;
    const int lane = tid & 63;
    const int wave = tid >> 6;
    const int wr = wave >> 1, wc = wave & 1;
    const int m0 = blockIdx.y * 128, n0 = blockIdx.x * 128;
    const int lrow = lane & 15;
    const int lk = (lane >> 4) * 8;

    f32x4 zero = {0.f, 0.f, 0.f, 0.f};
    f32x4 acc[4][4];
    #pragma unroll
    for (int m = 0; m < 4; ++m)
        #pragma unroll
        for (int n = 0; n < 4; ++n) acc[m][n] = zero;

    const int srow = tid >> 2;            // 0..63
    const int skc = (tid & 3) * 8;        // 0,8,16,24
    const int ldsbase = (tid & 192) * 8;  // wave * 512 elements

    for (int k0 = 0; k0 < K; k0 += 32) {
        const ushort* ga0 = A  + (size_t)(m0 + srow) * K + k0 + skc;
        const ushort* ga1 = A  + (size_t)(m0 + 64 + srow) * K + k0 + skc;
        const ushort* gb0 = Bt + (size_t)(n0 + srow) * K + k0 + skc;
        const ushort* gb1 = Bt + (size_t)(n0 + 64 + srow) * K + k0 + skc;
        glds16(ga0, &As[ldsbase]);
        glds16(ga1, &As[2048 + ldsbase]);
        glds16(gb0, &Bs[ldsbase]);
        glds16(gb1, &Bs[2048 + ldsbase]);
        __syncthreads();

        bf16x8 af[4], bv[4];
        #pragma unroll
        for (int m = 0; m < 4; ++m)
            af[m] = *reinterpret_cast<const bf16x8*>(&As[(wr * 64 + m * 16 + lrow) * 32 + lk]);
        #pragma unroll
        for (int n = 0; n < 4; ++n)
            bv[n] = *reinterpret_cast<const bf16x8*>(&Bs[(wc * 64 + n * 16 + lrow) * 32 + lk]);
        #pragma unroll
        for (int m = 0; m < 4; ++m)
            #pragma unroll
            for (int n = 0; n < 4; ++n)
                acc[m][n] = __builtin_amdgcn_mfma_f32_16x16x32_bf16(af[m], bv[n], acc[m][n], 0, 0, 0);
        __syncthreads();
    }

    #pragma unroll
    for (int n = 0; n < 4; ++n) {
        int col = n0 + wc * 64 + n * 16 + lrow;
        float bval = bias[col];
        #pragma unroll
        for (int m = 0; m < 4; ++m) {
            #pragma unroll
            for (int j = 0; j < 4; ++j) {
                int row = m0 + wr * 64 + m * 16 + (lane >> 4) * 4 + j;
                float v = acc[m][n][j] + bval;
                if (RELU) v = fmaxf(v, 0.0f);
                if (OUTBF) ((ushort*)Cout)[(size_t)row * N + col] = f2bf(v);
                else       ((float*)Cout)[(size_t)row * N + col] = v;
            }
        }
    }
}

// f32 [K][N] -> bf16 [N][K] (transpose + convert), 32x32 tiles
__global__ __launch_bounds__(256) void transpose_bf16(
    const float* __restrict__ in, ushort* __restrict__ out, int K, int N)
{
    __shared__ float t[32][33];
    int n0 = blockIdx.x * 32, k0 = blockIdx.y * 32;
    int tx = threadIdx.x & 31, ty = threadIdx.x >> 5;  // ty 0..7
    #pragma unroll
    for (int dy = 0; dy < 32; dy += 8)
        t[ty + dy][tx] = in[(size_t)(k0 + ty + dy) * N + n0 + tx];
    __syncthreads();
    #pragma unroll
    for (int dy = 0; dy < 32; dy += 8)
        out[(size_t)(n0 + ty + dy) * K + k0 + tx] = f2bf(t[tx][ty + dy]);
}

// flat f32 -> bf16, 4 elems/thread
__global__ __launch_bounds__(256) void conv_bf16x4(
    const float* __restrict__ in, ushort* __restrict__ out, int n4)
{
    int i = blockIdx.x * 256 + threadIdx.x;
    if (i >= n4) return;
    float4 v = reinterpret_cast<const float4*>(in)[i];
    uint32_t lo = (uint32_t)f2bf(v.x) | ((uint32_t)f2bf(v.y) << 16);
    uint32_t hi = (uint32_t)f2bf(v.z) | ((uint32_t)f2bf(v.w) << 16);
    reinterpret_cast<uint2*>(out)[i] = make_uint2(lo, hi);
}

// ---------------------------------------------------------------------------
// compute_M v2: lane = sample. Wave per (b,h,l); lane s computes its full
// 64-dot privately (Q row broadcast from LDS); ONE cross-lane reduce at end.
// ---------------------------------------------------------------------------
__global__ __launch_bounds__(256) void compute_M_kernel(
    const float* __restrict__ Q, const float* __restrict__ Kb,
    const int* __restrict__ idx, float* __restrict__ Mout)
{
    __shared__ float qs[4][64];
    const int tid = threadIdx.x;
    const int wid = tid >> 6;
    const int lane = tid & 63;
    const int task = blockIdx.x * 4 + wid;     // (b,h,l)
    const int l = task & (Lc - 1);
    const int bh = task >> 10;
    const int h = bh & (Hc - 1);
    const int b = bh >> 3;

    // stage Q row (same-wave write->read; compiler inserts lgkmcnt wait)
    qs[wid][lane] = Q[((size_t)(b * Lc + l) * Hc + h) * 64 + lane];

    const bool act = lane < Uc;
    int kl = act ? idx[l * Uc + lane] : 0;
    const float4* kr = reinterpret_cast<const float4*>(
        &Kb[((size_t)(b * Lc + kl) * Hc + h) * 64]);
    float dot = 0.0f;
    if (act) {
        #pragma unroll
        for (int d4 = 0; d4 < 16; ++d4) {
            float4 kv = kr[d4];
            float4 q4 = *reinterpret_cast<const float4*>(&qs[wid][d4 * 4]);
            dot += q4.x * kv.x + q4.y * kv.y + q4.z * kv.z + q4.w * kv.w;
        }
    }
    float mx = act ? dot : -INFINITY;
    float sm = act ? dot : 0.0f;
    #pragma unroll
    for (int off = 32; off; off >>= 1) {
        mx = fmaxf(mx, __shfl_xor(mx, off, 64));
        sm += __shfl_xor(sm, off, 64);
    }
    if (lane == 0) Mout[task] = mx - sm * (1.0f / Uc);
}

// ---------------------------------------------------------------------------
// Top-u per (b,h); builds rowmap. Tie-break lowest index. Block per (b,h).
// ---------------------------------------------------------------------------
__global__ __launch_bounds__(256) void topk_kernel(
    const float* __restrict__ Mvals, int* __restrict__ Mtop,
    int* __restrict__ rowmap)
{
    int bh = blockIdx.x;
    __shared__ float vals[Lc];
    __shared__ float rv[256];
    __shared__ int   ri[256];
    int t = threadIdx.x;
    for (int i = t; i < Lc; i += 256) {
        vals[i] = Mvals[(size_t)bh * Lc + i];
        rowmap[(size_t)bh * Lc + i] = -1;
    }
    __syncthreads();
    for (int j = 0; j < Uc; ++j) {
        float bv = -INFINITY; int bi = Lc;
        for (int i = t; i < Lc; i += 256) {
            float v = vals[i];
            if (v > bv) { bv = v; bi = i; }
        }
        rv[t] = bv; ri[t] = bi;
        __syncthreads();
        for (int s = 128; s; s >>= 1) {
            if (t < s) {
                float v2 = rv[t + s]; int i2 = ri[t + s];
                if (v2 > rv[t] || (v2 == rv[t] && i2 < ri[t])) { rv[t] = v2; ri[t] = i2; }
            }
            __syncthreads();
        }
        if (t == 0) {
            int bidx = ri[0];
            Mtop[bh * Uc + j] = bidx;
            rowmap[(size_t)bh * Lc + bidx] = j;
            vals[bidx] = -INFINITY;
        }
        __syncthreads();
    }
}

// ---------------------------------------------------------------------------
// QK scores v2: block per (b,h,l-chunk of 256). Thread owns one K row (read
// once), 35 accumulators; Q_reduce rows broadcast from LDS.
// scores[bh,j,l] = dot(Q[qpos_j], K[l]) / 8   (raw, softmax separate)
// ---------------------------------------------------------------------------
__global__ __launch_bounds__(256) void qk_scores_kernel(
    const float* __restrict__ Q, const float* __restrict__ Kb,
    const int* __restrict__ Mtop, float* __restrict__ scores)
{
    const int bh = blockIdx.x >> 2;
    const int l0 = (blockIdx.x & 3) * 256;
    const int h = bh & (Hc - 1), b = bh >> 3;
    __shared__ int qpos[Uc];
    __shared__ float Qs[Uc][64];
    const int t = threadIdx.x;
    if (t < Uc) qpos[t] = Mtop[bh * Uc + t];
    __syncthreads();
    for (int i = t; i < Uc * 64; i += 256) {
        int j = i >> 6, d = i & 63;
        Qs[j][d] = Q[((size_t)(b * Lc + qpos[j]) * Hc + h) * 64 + d];
    }
    __syncthreads();

    const int l = l0 + t;
    const float4* kr = reinterpret_cast<const float4*>(
        &Kb[((size_t)(b * Lc + l) * Hc + h) * 64]);
    float acc[Uc] = {};
    #pragma unroll 4
    for (int d4 = 0; d4 < 16; ++d4) {
        float4 kv = kr[d4];
        #pragma unroll
        for (int j = 0; j < Uc; ++j) {
            float4 q4 = *reinterpret_cast<const float4*>(&Qs[j][d4 * 4]);
            acc[j] += q4.x * kv.x + q4.y * kv.y + q4.z * kv.z + q4.w * kv.w;
        }
    }
    #pragma unroll
    for (int j = 0; j < Uc; ++j)
        scores[((size_t)bh * Uc + j) * Lc + l] = acc[j] * 0.125f;
}

// softmax in place over each row of scores. Block per (b,h,j).
__global__ __launch_bounds__(256) void softmax_rows_kernel(float* __restrict__ scores)
{
    const size_t row = blockIdx.x;
    const int t = threadIdx.x;
    float* p = scores + row * Lc;
    float v[4];
    float lmax = -INFINITY;
    #pragma unroll
    for (int c = 0; c < 4; ++c) { v[c] = p[t + c * 256]; lmax = fmaxf(lmax, v[c]); }
    __shared__ float red[256];
    red[t] = lmax; __syncthreads();
    for (int s = 128; s; s >>= 1) { if (t < s) red[t] = fmaxf(red[t], red[t + s]); __syncthreads(); }
    float m = red[0];
    __syncthreads();
    float lsum = 0.0f;
    #pragma unroll
    for (int c = 0; c < 4; ++c) { v[c] = expf(v[c] - m); lsum += v[c]; }
    red[t] = lsum; __syncthreads();
    for (int s = 128; s; s >>= 1) { if (t < s) red[t] += red[t + s]; __syncthreads(); }
    float inv = 1.0f / red[0];
    #pragma unroll
    for (int c = 0; c < 4; ++c) p[t + c * 256] = v[c] * inv;
}

// Vmean[b,h,d] over l. Block per (b,h).
__global__ __launch_bounds__(256) void vmean_kernel(
    const float* __restrict__ V, float* __restrict__ Vm)
{
    int bh = blockIdx.x; int h = bh & (Hc - 1); int b = bh >> 3;
    int t = threadIdx.x; int d = t & 63; int part = t >> 6;
    float s = 0.0f;
    for (int l = part; l < Lc; l += 4)
        s += V[((size_t)(b * Lc + l) * Hc + h) * 64 + d];
    __shared__ float red[256];
    red[t] = s; __syncthreads();
    if (t < 64) {
        float tot = red[t] + red[t + 64] + red[t + 128] + red[t + 192];
        Vm[bh * 64 + t] = tot * (1.0f / Lc);
    }
}

// ctx[b,l,h,d] = bf16(Vmean[b,h,d])
__global__ __launch_bounds__(256) void ctx_fill_bf(
    ushort* __restrict__ ctx, const float* __restrict__ Vm)
{
    size_t i = (size_t)blockIdx.x * 256 + threadIdx.x;
    int d = (int)(i & 63);
    int h = (int)((i >> 6) & 7);
    int b = (int)(i >> 19);
    ctx[i] = f2bf(Vm[(b * 8 + h) * 64 + d]);
}

// ctx[b,qpos,h,:] = bf16( attn[b,h,j,:] @ V[b,h,:,:] ). Block per (b,h,j).
__global__ __launch_bounds__(256) void ctx_scatter_bf(
    const float* __restrict__ attn, const float* __restrict__ V,
    const int* __restrict__ Mtop, ushort* __restrict__ ctx)
{
    int task = blockIdx.x;
    int j = task % Uc; int bh = task / Uc;
    int h = bh & (Hc - 1); int b = bh >> 3;
    int qpos = Mtop[bh * Uc + j];
    int t = threadIdx.x; int d = t & 63; int part = t >> 6;
    float s = 0.0f;
    for (int l = part; l < Lc; l += 4)
        s += attn[(size_t)task * Lc + l] * V[((size_t)(b * Lc + l) * Hc + h) * 64 + d];
    __shared__ float red[256];
    red[t] = s; __syncthreads();
    if (t < 64) {
        float tot = red[t] + red[t + 64] + red[t + 128] + red[t + 192];
        ctx[((size_t)(b * Lc + qpos) * Hc + h) * 64 + t] = f2bf(tot);
    }
}

// y = LN(a+b)*g+beta over DM=512; optional bf16 copy. Block per row.
__global__ __launch_bounds__(256) void ln_residual_kernel(
    const float* __restrict__ a, const float* __restrict__ bsrc,
    const float* __restrict__ g, const float* __restrict__ beta,
    float* __restrict__ y, ushort* __restrict__ ybf)
{
    int row = blockIdx.x;
    int t = threadIdx.x;
    const float* ar = a + (size_t)row * DMc;
    const float* br = bsrc + (size_t)row * DMc;
    float v0 = ar[t] + br[t];
    float v1 = ar[t + 256] + br[t + 256];
    __shared__ float red[256];
    red[t] = v0 + v1; __syncthreads();
    for (int s = 128; s; s >>= 1) { if (t < s) red[t] += red[t + s]; __syncthreads(); }
    float mean = red[0] * (1.0f / DMc);
    __syncthreads();
    float d0 = v0 - mean, d1 = v1 - mean;
    red[t] = d0 * d0 + d1 * d1; __syncthreads();
    for (int s = 128; s; s >>= 1) { if (t < s) red[t] += red[t + s]; __syncthreads(); }
    float inv = rsqrtf(red[0] * (1.0f / DMc) + 1e-5f);
    float o0 = g[t] * d0 * inv + beta[t];
    float o1 = g[t + 256] * d1 * inv + beta[t + 256];
    y[(size_t)row * DMc + t]       = o0;
    y[(size_t)row * DMc + t + 256] = o1;
    if (ybf) {
        ybf[(size_t)row * DMc + t]       = f2bf(o0);
        ybf[(size_t)row * DMc + t + 256] = f2bf(o1);
    }
}

// score[b,h,l,:] = attn row if selected else 1/L. Block per (b,h,l).
__global__ __launch_bounds__(256) void score_write_kernel(
    const float* __restrict__ attn, const int* __restrict__ rowmap,
    float* __restrict__ score)
{
    size_t row = blockIdx.x;
    int bh = (int)(row >> 10);
    int j = rowmap[row];
    int t = threadIdx.x;
    float4* dst = reinterpret_cast<float4*>(score + row * Lc);
    if (j >= 0) {
        const float4* src = reinterpret_cast<const float4*>(attn + ((size_t)bh * Uc + j) * Lc);
        dst[t] = src[t];
    } else {
        const float iv = 1.0f / (float)Lc;
        dst[t] = make_float4(iv, iv, iv, iv);
    }
}

// ---------------------------------------------------------------------------
extern "C" void kernel_launch(void* const* d_in, const int* in_sizes, int n_in,
                              void* d_out, int out_size, void* d_ws, size_t ws_size,
                              hipStream_t stream)
{
    const float* x     = (const float*)d_in[0];
    const float* Wq    = (const float*)d_in[1];
    const float* bq    = (const float*)d_in[2];
    const float* Wk    = (const float*)d_in[3];
    const float* bk    = (const float*)d_in[4];
    const float* Wv    = (const float*)d_in[5];
    const float* bv    = (const float*)d_in[6];
    const float* Wo    = (const float*)d_in[7];
    const float* bo    = (const float*)d_in[8];
    const float* g1    = (const float*)d_in[9];
    const float* beta1 = (const float*)d_in[10];
    const float* W1    = (const float*)d_in[11];
    const float* bf1   = (const float*)d_in[12];
    const float* W2    = (const float*)d_in[13];
    const float* bf2   = (const float*)d_in[14];
    const float* g2    = (const float*)d_in[15];
    const float* beta2 = (const float*)d_in[16];
    const int* index_sample = (const int*)d_in[17];

    const size_t NTOK = (size_t)Bc * Lc;            // 16384
    const size_t QKV_SZ = NTOK * DMc;               // 8,388,608
    const size_t ATTN_SZ = (size_t)Bc * Hc * Uc * Lc;
    const size_t HID_SZ = NTOK * DHc;               // 33,554,432

    char* p = (char*)d_ws;
    auto alloc = [&](size_t bytes) { char* r = p; p += (bytes + 255) & ~(size_t)255; return r; };
    float*  Q      = (float*) alloc(QKV_SZ * 4);
    float*  Kf     = (float*) alloc(QKV_SZ * 4);   // K, later x1 (f32)
    float*  V      = (float*) alloc(QKV_SZ * 4);   // V, later proj/ffn out
    float*  attn   = (float*) alloc(ATTN_SZ * 4);
    ushort* hidden = (ushort*)alloc(HID_SZ * 2);
    ushort* xbf    = (ushort*)alloc(QKV_SZ * 2);
    ushort* ctxbf  = (ushort*)alloc(QKV_SZ * 2);
    ushort* x1bf   = (ushort*)alloc(QKV_SZ * 2);
    ushort* Wqt    = (ushort*)alloc((size_t)512 * 512 * 2);
    ushort* Wkt    = (ushort*)alloc((size_t)512 * 512 * 2);
    ushort* Wvt    = (ushort*)alloc((size_t)512 * 512 * 2);
    ushort* Wot    = (ushort*)alloc((size_t)512 * 512 * 2);
    ushort* W1t    = (ushort*)alloc((size_t)512 * 2048 * 2);
    ushort* W2t    = (ushort*)alloc((size_t)512 * 2048 * 2);
    float*  Mbuf   = (float*) alloc((size_t)Bc * Hc * Lc * 4);
    float*  Vm     = (float*) alloc((size_t)Bc * Hc * 64 * 4);
    int*    rowmap = (int*)   alloc((size_t)Bc * Hc * Lc * 4);
    int*    Mtop   = (int*)   alloc((size_t)Bc * Hc * 64 * 4);

    float* x2_out    = (float*)d_out;
    float* score_out = x2_out + QKV_SZ;

    dim3 blk(256);

    // bf16 conversions
    conv_bf16x4<<<(int)(QKV_SZ / 4 / 256), blk, 0, stream>>>(x, xbf, (int)(QKV_SZ / 4));
    transpose_bf16<<<dim3(16, 16), blk, 0, stream>>>(Wq, Wqt, 512, 512);
    transpose_bf16<<<dim3(16, 16), blk, 0, stream>>>(Wk, Wkt, 512, 512);
    transpose_bf16<<<dim3(16, 16), blk, 0, stream>>>(Wv, Wvt, 512, 512);
    transpose_bf16<<<dim3(16, 16), blk, 0, stream>>>(Wo, Wot, 512, 512);
    transpose_bf16<<<dim3(64, 16), blk, 0, stream>>>(W1, W1t, 512, 2048);
    transpose_bf16<<<dim3(16, 64), blk, 0, stream>>>(W2, W2t, 2048, 512);

    // QKV projections (f32 out)
    gemm_mfma<0,0><<<dim3(4, 128), blk, 0, stream>>>(xbf, Wqt, bq, Q,  (int)NTOK, 512, 512);
    gemm_mfma<0,0><<<dim3(4, 128), blk, 0, stream>>>(xbf, Wkt, bk, Kf, (int)NTOK, 512, 512);
    gemm_mfma<0,0><<<dim3(4, 128), blk, 0, stream>>>(xbf, Wvt, bv, V,  (int)NTOK, 512, 512);

    // ProbSparse selection
    compute_M_kernel<<<(Bc * Hc * Lc) / 4, blk, 0, stream>>>(Q, Kf, index_sample, Mbuf);
    topk_kernel<<<Bc * Hc, blk, 0, stream>>>(Mbuf, Mtop, rowmap);

    // reduced-Q scores + softmax (two phase)
    qk_scores_kernel<<<Bc * Hc * 4, blk, 0, stream>>>(Q, Kf, Mtop, attn);
    softmax_rows_kernel<<<Bc * Hc * Uc, blk, 0, stream>>>(attn);

    // context (bf16)
    vmean_kernel<<<Bc * Hc, blk, 0, stream>>>(V, Vm);
    ctx_fill_bf<<<(int)(QKV_SZ / 256), blk, 0, stream>>>(ctxbf, Vm);
    ctx_scatter_bf<<<Bc * Hc * Uc, blk, 0, stream>>>(attn, V, Mtop, ctxbf);

    // output projection + LN1 (x1 -> Kf f32 + x1bf)
    gemm_mfma<0,0><<<dim3(4, 128), blk, 0, stream>>>(ctxbf, Wot, bo, V, (int)NTOK, 512, 512);
    ln_residual_kernel<<<(int)NTOK, blk, 0, stream>>>(V, x, g1, beta1, Kf, x1bf);

    // FFN: GEMM1 writes bf16 hidden directly (relu), GEMM2 f32
    gemm_mfma<1,1><<<dim3(16, 128), blk, 0, stream>>>(x1bf, W1t, bf1, hidden, (int)NTOK, 2048, 512);
    gemm_mfma<0,0><<<dim3(4, 128), blk, 0, stream>>>(hidden, W2t, bf2, V, (int)NTOK, 512, 2048);
    ln_residual_kernel<<<(int)NTOK, blk, 0, stream>>>(V, Kf, g2, beta2, x2_out, nullptr);

    // score output
    score_write_kernel<<<Bc * Hc * Lc, blk, 0, stream>>>(attn, rowmap, score_out);
}

// Round 4
// 811.691 us; speedup vs baseline: 3.0065x; 1.1380x over previous
//
#include <hip/hip_runtime.h>
#include <cstdint>
#include <cstddef>

// Problem constants
#define Bc 16
#define Lc 1024
#define DMc 512
#define Hc 8
#define DHc 2048
#define Uc 35        // FACTOR*ceil(ln(L)) = 5*7, fixed by problem setup

typedef __attribute__((ext_vector_type(8))) short bf16x8;
typedef __attribute__((ext_vector_type(4))) float f32x4;

__device__ __forceinline__ ushort f2bf(float f) {
    union { float f; uint32_t u; } v; v.f = f;
    uint32_t r = v.u + 0x7FFF + ((v.u >> 16) & 1);   // round-to-nearest-even
    return (ushort)(r >> 16);
}
__device__ __forceinline__ float bf2f(ushort u) {
    union { uint32_t i; float f; } v; v.i = ((uint32_t)u) << 16; return v.f;
}

// async global->LDS, 16 bytes per lane; LDS dest must be wave-uniform base
__device__ __forceinline__ void glds16(const ushort* g, ushort* l) {
    __builtin_amdgcn_global_load_lds(
        (__attribute__((address_space(1))) void*)(void*)const_cast<ushort*>(g),
        (__attribute__((address_space(3))) void*)l, 16, 0, 0);
}

// ---------------------------------------------------------------------------
// bf16 MFMA GEMM (m97 structure): C[M,N] = A[M,K] @ Bt[N,K]^T + bias.
// 128x128 tile, BK=32, 256 threads (4 waves, 2x2), 4x4 16x16x32 frags/wave.
// MODE: 0 = f32 out0; 1 = bf16 out0; 2 = relu+bf16 out0;
//       3 = QKV split: col<1024 -> bf16 out0 [row][1024], else f32 out1 [row][512]
// ---------------------------------------------------------------------------
template<int MODE>
__global__ __launch_bounds__(256) void gemm_mfma(
    const ushort* __restrict__ A, const ushort* __restrict__ Bt,
    const float* __restrict__ bias, void* __restrict__ out0,
    void* __restrict__ out1, int M, int N, int K)
{
    __shared__ ushort As[128 * 32];
    __shared__ ushort Bs[128 * 32];
    const int tid = threadIdx.x;
    const int lane = tid & 63;
    const int wave = tid >> 6;
    const int wr = wave >> 1, wc = wave & 1;
    const int m0 = blockIdx.y * 128, n0 = blockIdx.x * 128;
    const int lrow = lane & 15;
    const int lk = (lane >> 4) * 8;

    f32x4 zero = {0.f, 0.f, 0.f, 0.f};
    f32x4 acc[4][4];
    #pragma unroll
    for (int m = 0; m < 4; ++m)
        #pragma unroll
        for (int n = 0; n < 4; ++n) acc[m][n] = zero;

    const int srow = tid >> 2;            // 0..63
    const int skc = (tid & 3) * 8;        // 0,8,16,24
    const int ldsbase = (tid & 192) * 8;  // wave * 512 elements

    for (int k0 = 0; k0 < K; k0 += 32) {
        const ushort* ga0 = A  + (size_t)(m0 + srow) * K + k0 + skc;
        const ushort* ga1 = A  + (size_t)(m0 + 64 + srow) * K + k0 + skc;
        const ushort* gb0 = Bt + (size_t)(n0 + srow) * K + k0 + skc;
        const ushort* gb1 = Bt + (size_t)(n0 + 64 + srow) * K + k0 + skc;
        glds16(ga0, &As[ldsbase]);
        glds16(ga1, &As[2048 + ldsbase]);
        glds16(gb0, &Bs[ldsbase]);
        glds16(gb1, &Bs[2048 + ldsbase]);
        __syncthreads();

        bf16x8 af[4], bv[4];
        #pragma unroll
        for (int m = 0; m < 4; ++m)
            af[m] = *reinterpret_cast<const bf16x8*>(&As[(wr * 64 + m * 16 + lrow) * 32 + lk]);
        #pragma unroll
        for (int n = 0; n < 4; ++n)
            bv[n] = *reinterpret_cast<const bf16x8*>(&Bs[(wc * 64 + n * 16 + lrow) * 32 + lk]);
        #pragma unroll
        for (int m = 0; m < 4; ++m)
            #pragma unroll
            for (int n = 0; n < 4; ++n)
                acc[m][n] = __builtin_amdgcn_mfma_f32_16x16x32_bf16(af[m], bv[n], acc[m][n], 0, 0, 0);
        __syncthreads();
    }

    #pragma unroll
    for (int n = 0; n < 4; ++n) {
        int col = n0 + wc * 64 + n * 16 + lrow;
        float bval = bias[col];
        #pragma unroll
        for (int m = 0; m < 4; ++m) {
            #pragma unroll
            for (int j = 0; j < 4; ++j) {
                int row = m0 + wr * 64 + m * 16 + (lane >> 4) * 4 + j;
                float v = acc[m][n][j] + bval;
                if (MODE == 2) v = fmaxf(v, 0.0f);
                if (MODE == 0)
                    ((float*)out0)[(size_t)row * N + col] = v;
                else if (MODE == 1 || MODE == 2)
                    ((ushort*)out0)[(size_t)row * N + col] = f2bf(v);
                else {  // MODE 3
                    if (col < 1024) ((ushort*)out0)[(size_t)row * 1024 + col] = f2bf(v);
                    else            ((float*)out1)[(size_t)row * 512 + (col - 1024)] = v;
                }
            }
        }
    }
}

// ---------------------------------------------------------------------------
// Fused prep: x->bf16, 6 weight transposes (to [N][K] bf16), bias concat.
// Block ranges select the job.
// ---------------------------------------------------------------------------
__device__ __forceinline__ void tr_tile(
    const float* __restrict__ in, ushort* __restrict__ out,
    int K, int N, int bx, int by, float (*t)[33], int tid)
{
    int n0 = bx * 32, k0 = by * 32;
    int tx = tid & 31, ty = tid >> 5;
    #pragma unroll
    for (int dy = 0; dy < 32; dy += 8)
        t[ty + dy][tx] = in[(size_t)(k0 + ty + dy) * N + n0 + tx];
    __syncthreads();
    #pragma unroll
    for (int dy = 0; dy < 32; dy += 8)
        out[(size_t)(n0 + ty + dy) * K + k0 + tx] = f2bf(t[tx][ty + dy]);
}

__global__ __launch_bounds__(256) void prep_kernel(
    const float* __restrict__ x,
    const float* __restrict__ Wq, const float* __restrict__ Wk,
    const float* __restrict__ Wv, const float* __restrict__ Wo,
    const float* __restrict__ W1, const float* __restrict__ W2,
    const float* __restrict__ bq, const float* __restrict__ bk,
    const float* __restrict__ bv,
    ushort* __restrict__ xbf, ushort* __restrict__ Wqkvt,
    ushort* __restrict__ Wot, ushort* __restrict__ W1t,
    ushort* __restrict__ W2t, float* __restrict__ bcat)
{
    __shared__ float t[32][33];
    const int tid = threadIdx.x;
    int bid = blockIdx.x;
    if (bid < 8192) {   // x -> bf16 (float4 per thread)
        int i = bid * 256 + tid;
        float4 v = reinterpret_cast<const float4*>(x)[i];
        uint32_t lo = (uint32_t)f2bf(v.x) | ((uint32_t)f2bf(v.y) << 16);
        uint32_t hi = (uint32_t)f2bf(v.z) | ((uint32_t)f2bf(v.w) << 16);
        reinterpret_cast<uint2*>(xbf)[i] = make_uint2(lo, hi);
        return;
    }
    bid -= 8192;
    if (bid < 256) { tr_tile(Wq, Wqkvt,                 512, 512, bid & 15, bid >> 4, t, tid); return; }
    bid -= 256;
    if (bid < 256) { tr_tile(Wk, Wqkvt + 512 * 512,     512, 512, bid & 15, bid >> 4, t, tid); return; }
    bid -= 256;
    if (bid < 256) { tr_tile(Wv, Wqkvt + 1024 * 512,    512, 512, bid & 15, bid >> 4, t, tid); return; }
    bid -= 256;
    if (bid < 256) { tr_tile(Wo, Wot,                   512, 512, bid & 15, bid >> 4, t, tid); return; }
    bid -= 256;
    if (bid < 1024) { tr_tile(W1, W1t,                  512, 2048, bid & 63, bid >> 6, t, tid); return; }
    bid -= 1024;
    if (bid < 1024) { tr_tile(W2, W2t,                  2048, 512, bid & 15, bid >> 4, t, tid); return; }
    // bias concat (one block)
    for (int i = tid; i < 1536; i += 256)
        bcat[i] = (i < 512) ? bq[i] : (i < 1024) ? bk[i - 512] : bv[i - 1024];
}

// fill score_out with 1/L (pure BW; selected rows overwritten later)
__global__ __launch_bounds__(256) void fill_score_kernel(float* __restrict__ s)
{
    const float iv = 1.0f / (float)Lc;
    float4 v = make_float4(iv, iv, iv, iv);
    size_t i = (size_t)blockIdx.x * 256 + threadIdx.x;
    const size_t nthreads = (size_t)32768 * 256;
    float4* p = reinterpret_cast<float4*>(s);
    #pragma unroll
    for (int c = 0; c < 4; ++c) p[i + c * nthreads] = v;
}

// ---------------------------------------------------------------------------
// compute_M: lane = sample. Wave per (b,h,l). Q,K are bf16 rows in QK buffer
// laid out [b*L+l][1024] = [Q(h*64+d) | K(h*64+d)+512].
// ---------------------------------------------------------------------------
__global__ __launch_bounds__(256) void compute_M_kernel(
    const ushort* __restrict__ QK, const int* __restrict__ idx,
    float* __restrict__ Mout)
{
    __shared__ float qs[4][64];
    const int tid = threadIdx.x;
    const int wid = tid >> 6;
    const int lane = tid & 63;
    const int task = blockIdx.x * 4 + wid;     // (b,h,l)
    const int l = task & (Lc - 1);
    const int bh = task >> 10;
    const int h = bh & (Hc - 1);
    const int b = bh >> 3;

    qs[wid][lane] = bf2f(QK[(size_t)(b * Lc + l) * 1024 + h * 64 + lane]);

    const bool act = lane < Uc;
    int kl = act ? idx[l * Uc + lane] : 0;
    const bf16x8* kr = reinterpret_cast<const bf16x8*>(
        QK + (size_t)(b * Lc + kl) * 1024 + 512 + h * 64);
    float dot = 0.0f;
    if (act) {
        #pragma unroll
        for (int c = 0; c < 8; ++c) {
            bf16x8 kv = kr[c];
            #pragma unroll
            for (int e = 0; e < 8; ++e)
                dot += qs[wid][c * 8 + e] * bf2f((ushort)kv[e]);
        }
    }
    float mx = act ? dot : -INFINITY;
    float sm = act ? dot : 0.0f;
    #pragma unroll
    for (int off = 32; off; off >>= 1) {
        mx = fmaxf(mx, __shfl_xor(mx, off, 64));
        sm += __shfl_xor(sm, off, 64);
    }
    if (lane == 0) Mout[task] = mx - sm * (1.0f / Uc);
}

// ---------------------------------------------------------------------------
// Top-u per (b,h). Tie-break lowest index. Block per (b,h).
// ---------------------------------------------------------------------------
__global__ __launch_bounds__(256) void topk_kernel(
    const float* __restrict__ Mvals, int* __restrict__ Mtop)
{
    int bh = blockIdx.x;
    __shared__ float vals[Lc];
    __shared__ float rv[256];
    __shared__ int   ri[256];
    int t = threadIdx.x;
    for (int i = t; i < Lc; i += 256)
        vals[i] = Mvals[(size_t)bh * Lc + i];
    __syncthreads();
    for (int j = 0; j < Uc; ++j) {
        float bv = -INFINITY; int bi = Lc;
        for (int i = t; i < Lc; i += 256) {
            float v = vals[i];
            if (v > bv) { bv = v; bi = i; }
        }
        rv[t] = bv; ri[t] = bi;
        __syncthreads();
        for (int s = 128; s; s >>= 1) {
            if (t < s) {
                float v2 = rv[t + s]; int i2 = ri[t + s];
                if (v2 > rv[t] || (v2 == rv[t] && i2 < ri[t])) { rv[t] = v2; ri[t] = i2; }
            }
            __syncthreads();
        }
        if (t == 0) {
            int bidx = ri[0];
            Mtop[bh * Uc + j] = bidx;
            vals[bidx] = -INFINITY;
        }
        __syncthreads();
    }
}

// ---------------------------------------------------------------------------
// QK scores: block per (b,h, l-chunk of 256). Thread owns one K row (bf16,
// read once); Q_reduce rows broadcast from LDS (f32).
// ---------------------------------------------------------------------------
__global__ __launch_bounds__(256) void qk_scores_kernel(
    const ushort* __restrict__ QK, const int* __restrict__ Mtop,
    float* __restrict__ scores)
{
    const int bh = blockIdx.x >> 2;
    const int l0 = (blockIdx.x & 3) * 256;
    const int h = bh & (Hc - 1), b = bh >> 3;
    __shared__ int qpos[Uc];
    __shared__ float Qs[Uc][64];
    const int t = threadIdx.x;
    if (t < Uc) qpos[t] = Mtop[bh * Uc + t];
    __syncthreads();
    for (int i = t; i < Uc * 64; i += 256) {
        int j = i >> 6, d = i & 63;
        Qs[j][d] = bf2f(QK[(size_t)(b * Lc + qpos[j]) * 1024 + h * 64 + d]);
    }
    __syncthreads();

    const int l = l0 + t;
    const bf16x8* kr = reinterpret_cast<const bf16x8*>(
        QK + (size_t)(b * Lc + l) * 1024 + 512 + h * 64);
    float acc[Uc] = {};
    #pragma unroll
    for (int c = 0; c < 8; ++c) {
        bf16x8 kv = kr[c];
        float kf[8];
        #pragma unroll
        for (int e = 0; e < 8; ++e) kf[e] = bf2f((ushort)kv[e]);
        #pragma unroll
        for (int j = 0; j < Uc; ++j) {
            float s = 0.0f;
            #pragma unroll
            for (int e = 0; e < 8; ++e) s += Qs[j][c * 8 + e] * kf[e];
            acc[j] += s;
        }
    }
    #pragma unroll
    for (int j = 0; j < Uc; ++j)
        scores[((size_t)bh * Uc + j) * Lc + l] = acc[j] * 0.125f;
}

// softmax in place over attn row; also scatter result into score_out.
__global__ __launch_bounds__(256) void softmax_scatter_kernel(
    float* __restrict__ attn, const int* __restrict__ Mtop,
    float* __restrict__ score_out)
{
    const int task = blockIdx.x;               // bh*Uc + j
    const int j = task % Uc, bh = task / Uc;
    const int qpos = Mtop[bh * Uc + j];
    const int t = threadIdx.x;
    float* p = attn + (size_t)task * Lc;
    float v[4];
    float lmax = -INFINITY;
    #pragma unroll
    for (int c = 0; c < 4; ++c) { v[c] = p[t + c * 256]; lmax = fmaxf(lmax, v[c]); }
    __shared__ float red[256];
    red[t] = lmax; __syncthreads();
    for (int s = 128; s; s >>= 1) { if (t < s) red[t] = fmaxf(red[t], red[t + s]); __syncthreads(); }
    float m = red[0];
    __syncthreads();
    float lsum = 0.0f;
    #pragma unroll
    for (int c = 0; c < 4; ++c) { v[c] = expf(v[c] - m); lsum += v[c]; }
    red[t] = lsum; __syncthreads();
    for (int s = 128; s; s >>= 1) { if (t < s) red[t] += red[t + s]; __syncthreads(); }
    float inv = 1.0f / red[0];
    float* so = score_out + ((size_t)bh * Lc + qpos) * Lc;
    #pragma unroll
    for (int c = 0; c < 4; ++c) {
        float r = v[c] * inv;
        p[t + c * 256] = r;
        so[t + c * 256] = r;
    }
}

// Vmean[b,h,d] over l. Block per (b,h).
__global__ __launch_bounds__(256) void vmean_kernel(
    const float* __restrict__ V, float* __restrict__ Vm)
{
    int bh = blockIdx.x; int h = bh & (Hc - 1); int b = bh >> 3;
    int t = threadIdx.x; int d = t & 63; int part = t >> 6;
    float s = 0.0f;
    for (int l = part; l < Lc; l += 4)
        s += V[((size_t)(b * Lc + l) * Hc + h) * 64 + d];
    __shared__ float red[256];
    red[t] = s; __syncthreads();
    if (t < 64) {
        float tot = red[t] + red[t + 64] + red[t + 128] + red[t + 192];
        Vm[bh * 64 + t] = tot * (1.0f / Lc);
    }
}

// ctx[b,l,h,d] = bf16(Vmean[b,h,d]), 8 elems/thread
__global__ __launch_bounds__(256) void ctx_fill_bf(
    ushort* __restrict__ ctx, const float* __restrict__ Vm)
{
    size_t i = (size_t)blockIdx.x * 256 + threadIdx.x;  // over NTOK*512/8
    size_t e0 = i * 8;
    int d = (int)(e0 & 63);
    int h = (int)((e0 >> 6) & 7);
    int b = (int)(e0 >> 19);
    const float4* vm = reinterpret_cast<const float4*>(&Vm[(b * 8 + h) * 64 + d]);
    float4 a = vm[0], c = vm[1];
    uint4 o;
    o.x = (uint32_t)f2bf(a.x) | ((uint32_t)f2bf(a.y) << 16);
    o.y = (uint32_t)f2bf(a.z) | ((uint32_t)f2bf(a.w) << 16);
    o.z = (uint32_t)f2bf(c.x) | ((uint32_t)f2bf(c.y) << 16);
    o.w = (uint32_t)f2bf(c.z) | ((uint32_t)f2bf(c.w) << 16);
    *reinterpret_cast<uint4*>(ctx + e0) = o;
}

// ctx[b,qpos,h,:] = bf16( attn[bh,j,:] @ V[b,h,:,:] ). Block per (b,h,j).
__global__ __launch_bounds__(256) void ctx_scatter_bf(
    const float* __restrict__ attn, const float* __restrict__ V,
    const int* __restrict__ Mtop, ushort* __restrict__ ctx)
{
    int task = blockIdx.x;
    int j = task % Uc; int bh = task / Uc;
    int h = bh & (Hc - 1); int b = bh >> 3;
    int qpos = Mtop[bh * Uc + j];
    int t = threadIdx.x; int d = t & 63; int part = t >> 6;
    float s = 0.0f;
    for (int l = part; l < Lc; l += 4)
        s += attn[(size_t)task * Lc + l] * V[((size_t)(b * Lc + l) * Hc + h) * 64 + d];
    __shared__ float red[256];
    red[t] = s; __syncthreads();
    if (t < 64) {
        float tot = red[t] + red[t + 64] + red[t + 128] + red[t + 192];
        ctx[((size_t)(b * Lc + qpos) * Hc + h) * 64 + t] = f2bf(tot);
    }
}

// y = LN(a+b)*g+beta over DM=512; optional bf16 copy. Block per row.
__global__ __launch_bounds__(256) void ln_residual_kernel(
    const float* __restrict__ a, const float* __restrict__ bsrc,
    const float* __restrict__ g, const float* __restrict__ beta,
    float* __restrict__ y, ushort* __restrict__ ybf)
{
    int row = blockIdx.x;
    int t = threadIdx.x;
    const float* ar = a + (size_t)row * DMc;
    const float* br = bsrc + (size_t)row * DMc;
    float v0 = ar[t] + br[t];
    float v1 = ar[t + 256] + br[t + 256];
    __shared__ float red[256];
    red[t] = v0 + v1; __syncthreads();
    for (int s = 128; s; s >>= 1) { if (t < s) red[t] += red[t + s]; __syncthreads(); }
    float mean = red[0] * (1.0f / DMc);
    __syncthreads();
    float d0 = v0 - mean, d1 = v1 - mean;
    red[t] = d0 * d0 + d1 * d1; __syncthreads();
    for (int s = 128; s; s >>= 1) { if (t < s) red[t] += red[t + s]; __syncthreads(); }
    float inv = rsqrtf(red[0] * (1.0f / DMc) + 1e-5f);
    float o0 = g[t] * d0 * inv + beta[t];
    float o1 = g[t + 256] * d1 * inv + beta[t + 256];
    y[(size_t)row * DMc + t]       = o0;
    y[(size_t)row * DMc + t + 256] = o1;
    if (ybf) {
        ybf[(size_t)row * DMc + t]       = f2bf(o0);
        ybf[(size_t)row * DMc + t + 256] = f2bf(o1);
    }
}

// ---------------------------------------------------------------------------
extern "C" void kernel_launch(void* const* d_in, const int* in_sizes, int n_in,
                              void* d_out, int out_size, void* d_ws, size_t ws_size,
                              hipStream_t stream)
{
    const float* x     = (const float*)d_in[0];
    const float* Wq    = (const float*)d_in[1];
    const float* bq    = (const float*)d_in[2];
    const float* Wk    = (const float*)d_in[3];
    const float* bk    = (const float*)d_in[4];
    const float* Wv    = (const float*)d_in[5];
    const float* bv    = (const float*)d_in[6];
    const float* Wo    = (const float*)d_in[7];
    const float* bo    = (const float*)d_in[8];
    const float* g1    = (const float*)d_in[9];
    const float* beta1 = (const float*)d_in[10];
    const float* W1    = (const float*)d_in[11];
    const float* bf1   = (const float*)d_in[12];
    const float* W2    = (const float*)d_in[13];
    const float* bf2   = (const float*)d_in[14];
    const float* g2    = (const float*)d_in[15];
    const float* beta2 = (const float*)d_in[16];
    const int* index_sample = (const int*)d_in[17];

    const size_t NTOK = (size_t)Bc * Lc;            // 16384
    const size_t QKV_SZ = NTOK * DMc;               // 8,388,608
    const size_t ATTN_SZ = (size_t)Bc * Hc * Uc * Lc;
    const size_t HID_SZ = NTOK * DHc;

    char* p = (char*)d_ws;
    auto alloc = [&](size_t bytes) { char* r = p; p += (bytes + 255) & ~(size_t)255; return r; };
    ushort* QKbf   = (ushort*)alloc(NTOK * 1024 * 2);   // [tok][Q(512)|K(512)]
    float*  V      = (float*) alloc(QKV_SZ * 4);
    float*  attn   = (float*) alloc(ATTN_SZ * 4);
    ushort* hidden = (ushort*)alloc(HID_SZ * 2);
    ushort* xbf    = (ushort*)alloc(QKV_SZ * 2);
    ushort* ctxbf  = (ushort*)alloc(QKV_SZ * 2);
    ushort* x1bf   = (ushort*)alloc(QKV_SZ * 2);
    float*  projf  = (float*) alloc(QKV_SZ * 4);
    float*  x1f    = (float*) alloc(QKV_SZ * 4);
    float*  ffnf   = (float*) alloc(QKV_SZ * 4);
    ushort* Wqkvt  = (ushort*)alloc((size_t)1536 * 512 * 2);
    ushort* Wot    = (ushort*)alloc((size_t)512 * 512 * 2);
    ushort* W1t    = (ushort*)alloc((size_t)512 * 2048 * 2);
    ushort* W2t    = (ushort*)alloc((size_t)512 * 2048 * 2);
    float*  bcat   = (float*) alloc(1536 * 4);
    float*  Mbuf   = (float*) alloc((size_t)Bc * Hc * Lc * 4);
    float*  Vm     = (float*) alloc((size_t)Bc * Hc * 64 * 4);
    int*    Mtop   = (int*)   alloc((size_t)Bc * Hc * 64 * 4);

    float* x2_out    = (float*)d_out;
    float* score_out = x2_out + QKV_SZ;

    dim3 blk(256);

    // independent: default score fill + input prep
    fill_score_kernel<<<32768, blk, 0, stream>>>(score_out);
    prep_kernel<<<8192 + 4 * 256 + 2 * 1024 + 1, blk, 0, stream>>>(
        x, Wq, Wk, Wv, Wo, W1, W2, bq, bk, bv,
        xbf, Wqkvt, Wot, W1t, W2t, bcat);

    // fused QKV projection: Q,K -> bf16 QKbf, V -> f32
    gemm_mfma<3><<<dim3(12, 128), blk, 0, stream>>>(
        xbf, Wqkvt, bcat, QKbf, V, (int)NTOK, 1536, 512);

    // ProbSparse selection
    compute_M_kernel<<<(Bc * Hc * Lc) / 4, blk, 0, stream>>>(QKbf, index_sample, Mbuf);
    topk_kernel<<<Bc * Hc, blk, 0, stream>>>(Mbuf, Mtop);

    // reduced-Q scores + softmax (scatter into score_out too)
    qk_scores_kernel<<<Bc * Hc * 4, blk, 0, stream>>>(QKbf, Mtop, attn);
    softmax_scatter_kernel<<<Bc * Hc * Uc, blk, 0, stream>>>(attn, Mtop, score_out);

    // context (bf16)
    vmean_kernel<<<Bc * Hc, blk, 0, stream>>>(V, Vm);
    ctx_fill_bf<<<4096, blk, 0, stream>>>(ctxbf, Vm);
    ctx_scatter_bf<<<Bc * Hc * Uc, blk, 0, stream>>>(attn, V, Mtop, ctxbf);

    // output projection + LN1
    gemm_mfma<0><<<dim3(4, 128), blk, 0, stream>>>(
        ctxbf, Wot, bo, projf, nullptr, (int)NTOK, 512, 512);
    ln_residual_kernel<<<(int)NTOK, blk, 0, stream>>>(projf, x, g1, beta1, x1f, x1bf);

    // FFN
    gemm_mfma<2><<<dim3(16, 128), blk, 0, stream>>>(
        x1bf, W1t, bf1, hidden, nullptr, (int)NTOK, 2048, 512);
    gemm_mfma<0><<<dim3(4, 128), blk, 0, stream>>>(
        hidden, W2t, bf2, ffnf, nullptr, (int)NTOK, 512, 2048);
    ln_residual_kernel<<<(int)NTOK, blk, 0, stream>>>(ffnf, x1f, g2, beta2, x2_out, nullptr);
}

// Round 5
// 665.009 us; speedup vs baseline: 3.6697x; 1.2206x over previous
//
#include <hip/hip_runtime.h>
#include <cstdint>
#include <cstddef>

// Problem constants
#define Bc 16
#define Lc 1024
#define DMc 512
#define Hc 8
#define DHc 2048
#define Uc 35        // FACTOR*ceil(ln(L)) = 5*7, fixed by problem setup

typedef __attribute__((ext_vector_type(8))) short bf16x8;
typedef __attribute__((ext_vector_type(4))) float f32x4;

__device__ __forceinline__ ushort f2bf(float f) {
    union { float f; uint32_t u; } v; v.f = f;
    uint32_t r = v.u + 0x7FFF + ((v.u >> 16) & 1);   // round-to-nearest-even
    return (ushort)(r >> 16);
}
__device__ __forceinline__ float bf2f(ushort u) {
    union { uint32_t i; float f; } v; v.i = ((uint32_t)u) << 16; return v.f;
}

// async global->LDS, 16 bytes per lane; LDS dest must be wave-uniform base
__device__ __forceinline__ void glds16(const ushort* g, ushort* l) {
    __builtin_amdgcn_global_load_lds(
        (__attribute__((address_space(1))) void*)(void*)const_cast<ushort*>(g),
        (__attribute__((address_space(3))) void*)l, 16, 0, 0);
}

// ---------------------------------------------------------------------------
// bf16 MFMA GEMM: C[M,N] = A[M,K] @ Bt[N,K]^T + bias.
// 128x128 tile, BK=64 (2 barriers per 64 K / 32 MFMA), 256 threads (4 waves).
// 1-D grid with XCD-bijective remap (requires nwg % 8 == 0).
// MODE: 0 = f32 out0; 1 = bf16 out0; 2 = relu+bf16 out0;
//       3 = QKV split: col<1024 -> bf16 out0 [row][1024], else f32 out1 [row][512]
// ---------------------------------------------------------------------------
template<int MODE>
__global__ __launch_bounds__(256) void gemm_mfma(
    const ushort* __restrict__ A, const ushort* __restrict__ Bt,
    const float* __restrict__ bias, void* __restrict__ out0,
    void* __restrict__ out1, int M, int N, int K, int nxb)
{
    __shared__ ushort As[128 * 64];
    __shared__ ushort Bs[128 * 64];
    const int nwg = gridDim.x;
    int wg = blockIdx.x;
    wg = (wg & 7) * (nwg >> 3) + (wg >> 3);     // XCD swizzle (nwg%8==0)
    const int n0 = (wg % nxb) * 128;
    const int m0 = (wg / nxb) * 128;

    const int tid = threadIdx.x;
    const int lane = tid & 63;
    const int wave = tid >> 6;
    const int wr = wave >> 1, wc = wave & 1;
    const int lrow = lane & 15;
    const int lk = (lane >> 4) * 8;

    f32x4 zero = {0.f, 0.f, 0.f, 0.f};
    f32x4 acc[4][4];
    #pragma unroll
    for (int m = 0; m < 4; ++m)
        #pragma unroll
        for (int n = 0; n < 4; ++n) acc[m][n] = zero;

    const int srow = tid >> 3;            // 0..31 (row within 32-row chunk)
    const int skc = (tid & 7) * 8;        // 0..56 (k-offset, 8 elems = 16B)
    const int ldsb = (tid & 192) * 8;     // wave * 512 elems (8 rows)

    for (int k0 = 0; k0 < K; k0 += 64) {
        #pragma unroll
        for (int r = 0; r < 4; ++r) {
            glds16(A  + (size_t)(m0 + r * 32 + srow) * K + k0 + skc, &As[r * 2048 + ldsb]);
            glds16(Bt + (size_t)(n0 + r * 32 + srow) * K + k0 + skc, &Bs[r * 2048 + ldsb]);
        }
        __syncthreads();
        #pragma unroll
        for (int kk = 0; kk < 2; ++kk) {
            bf16x8 af[4], bv[4];
            #pragma unroll
            for (int m = 0; m < 4; ++m)
                af[m] = *reinterpret_cast<const bf16x8*>(&As[(wr * 64 + m * 16 + lrow) * 64 + kk * 32 + lk]);
            #pragma unroll
            for (int n = 0; n < 4; ++n)
                bv[n] = *reinterpret_cast<const bf16x8*>(&Bs[(wc * 64 + n * 16 + lrow) * 64 + kk * 32 + lk]);
            #pragma unroll
            for (int m = 0; m < 4; ++m)
                #pragma unroll
                for (int n = 0; n < 4; ++n)
                    acc[m][n] = __builtin_amdgcn_mfma_f32_16x16x32_bf16(af[m], bv[n], acc[m][n], 0, 0, 0);
        }
        __syncthreads();
    }

    #pragma unroll
    for (int n = 0; n < 4; ++n) {
        int col = n0 + wc * 64 + n * 16 + lrow;
        float bval = bias[col];
        #pragma unroll
        for (int m = 0; m < 4; ++m) {
            #pragma unroll
            for (int j = 0; j < 4; ++j) {
                int row = m0 + wr * 64 + m * 16 + (lane >> 4) * 4 + j;
                float v = acc[m][n][j] + bval;
                if (MODE == 2) v = fmaxf(v, 0.0f);
                if (MODE == 0)
                    ((float*)out0)[(size_t)row * N + col] = v;
                else if (MODE == 1 || MODE == 2)
                    ((ushort*)out0)[(size_t)row * N + col] = f2bf(v);
                else {  // MODE 3
                    if (col < 1024) ((ushort*)out0)[(size_t)row * 1024 + col] = f2bf(v);
                    else            ((float*)out1)[(size_t)row * 512 + (col - 1024)] = v;
                }
            }
        }
    }
}

// ---------------------------------------------------------------------------
// Fused prep: x->bf16, weight transposes to [N][K] bf16, bias concat.
// ---------------------------------------------------------------------------
__device__ __forceinline__ void tr_tile(
    const float* __restrict__ in, ushort* __restrict__ out,
    int K, int N, int bx, int by, float (*t)[33], int tid)
{
    int n0 = bx * 32, k0 = by * 32;
    int tx = tid & 31, ty = tid >> 5;
    #pragma unroll
    for (int dy = 0; dy < 32; dy += 8)
        t[ty + dy][tx] = in[(size_t)(k0 + ty + dy) * N + n0 + tx];
    __syncthreads();
    #pragma unroll
    for (int dy = 0; dy < 32; dy += 8)
        out[(size_t)(n0 + ty + dy) * K + k0 + tx] = f2bf(t[tx][ty + dy]);
}

__global__ __launch_bounds__(256) void prep_kernel(
    const float* __restrict__ x,
    const float* __restrict__ Wq, const float* __restrict__ Wk,
    const float* __restrict__ Wv, const float* __restrict__ Wo,
    const float* __restrict__ W1, const float* __restrict__ W2,
    const float* __restrict__ bq, const float* __restrict__ bk,
    const float* __restrict__ bv,
    ushort* __restrict__ xbf, ushort* __restrict__ Wqkvt,
    ushort* __restrict__ Wot, ushort* __restrict__ W1t,
    ushort* __restrict__ W2t, float* __restrict__ bcat)
{
    __shared__ float t[32][33];
    const int tid = threadIdx.x;
    int bid = blockIdx.x;
    if (bid < 8192) {   // x -> bf16 (float4 per thread)
        int i = bid * 256 + tid;
        float4 v = reinterpret_cast<const float4*>(x)[i];
        uint32_t lo = (uint32_t)f2bf(v.x) | ((uint32_t)f2bf(v.y) << 16);
        uint32_t hi = (uint32_t)f2bf(v.z) | ((uint32_t)f2bf(v.w) << 16);
        reinterpret_cast<uint2*>(xbf)[i] = make_uint2(lo, hi);
        return;
    }
    bid -= 8192;
    if (bid < 256) { tr_tile(Wq, Wqkvt,              512, 512, bid & 15, bid >> 4, t, tid); return; }
    bid -= 256;
    if (bid < 256) { tr_tile(Wk, Wqkvt + 512 * 512,  512, 512, bid & 15, bid >> 4, t, tid); return; }
    bid -= 256;
    if (bid < 256) { tr_tile(Wv, Wqkvt + 1024 * 512, 512, 512, bid & 15, bid >> 4, t, tid); return; }
    bid -= 256;
    if (bid < 256) { tr_tile(Wo, Wot,                512, 512, bid & 15, bid >> 4, t, tid); return; }
    bid -= 256;
    if (bid < 1024) { tr_tile(W1, W1t,               512, 2048, bid & 63, bid >> 6, t, tid); return; }
    bid -= 1024;
    if (bid < 1024) { tr_tile(W2, W2t,               2048, 512, bid & 15, bid >> 4, t, tid); return; }
    for (int i = tid; i < 1536; i += 256)
        bcat[i] = (i < 512) ? bq[i] : (i < 1024) ? bk[i - 512] : bv[i - 1024];
}

// fill score_out with 1/L (selected rows get raw S then probs later)
__global__ __launch_bounds__(256) void fill_score_kernel(float* __restrict__ s)
{
    const float iv = 1.0f / (float)Lc;
    float4 v = make_float4(iv, iv, iv, iv);
    size_t i = (size_t)blockIdx.x * 256 + threadIdx.x;
    const size_t nthreads = (size_t)32768 * 256;
    float4* p = reinterpret_cast<float4*>(s);
    #pragma unroll
    for (int c = 0; c < 4; ++c) p[i + c * nthreads] = v;
}

// ---------------------------------------------------------------------------
// compute_M: lane = sample. Wave per (b,h,l). QK: [b*L+l][Q(512)|K(512)] bf16.
// ---------------------------------------------------------------------------
__global__ __launch_bounds__(256) void compute_M_kernel(
    const ushort* __restrict__ QK, const int* __restrict__ idx,
    float* __restrict__ Mout)
{
    __shared__ float qs[4][64];
    const int tid = threadIdx.x;
    const int wid = tid >> 6;
    const int lane = tid & 63;
    const int task = blockIdx.x * 4 + wid;     // (b,h,l)
    const int l = task & (Lc - 1);
    const int bh = task >> 10;
    const int h = bh & (Hc - 1);
    const int b = bh >> 3;

    qs[wid][lane] = bf2f(QK[(size_t)(b * Lc + l) * 1024 + h * 64 + lane]);

    const bool act = lane < Uc;
    int kl = act ? idx[l * Uc + lane] : 0;
    const bf16x8* kr = reinterpret_cast<const bf16x8*>(
        QK + (size_t)(b * Lc + kl) * 1024 + 512 + h * 64);
    float dot = 0.0f;
    if (act) {
        #pragma unroll
        for (int c = 0; c < 8; ++c) {
            bf16x8 kv = kr[c];
            #pragma unroll
            for (int e = 0; e < 8; ++e)
                dot += qs[wid][c * 8 + e] * bf2f((ushort)kv[e]);
        }
    }
    float mx = act ? dot : -INFINITY;
    float sm = act ? dot : 0.0f;
    #pragma unroll
    for (int off = 32; off; off >>= 1) {
        mx = fmaxf(mx, __shfl_xor(mx, off, 64));
        sm += __shfl_xor(sm, off, 64);
    }
    if (lane == 0) Mout[task] = mx - sm * (1.0f / Uc);
}

// ---------------------------------------------------------------------------
// Top-u per (b,h). Tie-break lowest index. Block per (b,h).
// ---------------------------------------------------------------------------
__global__ __launch_bounds__(256) void topk_kernel(
    const float* __restrict__ Mvals, int* __restrict__ Mtop)
{
    int bh = blockIdx.x;
    __shared__ float vals[Lc];
    __shared__ float rv[256];
    __shared__ int   ri[256];
    int t = threadIdx.x;
    for (int i = t; i < Lc; i += 256)
        vals[i] = Mvals[(size_t)bh * Lc + i];
    __syncthreads();
    for (int j = 0; j < Uc; ++j) {
        float bv = -INFINITY; int bi = Lc;
        for (int i = t; i < Lc; i += 256) {
            float v = vals[i];
            if (v > bv) { bv = v; bi = i; }
        }
        rv[t] = bv; ri[t] = bi;
        __syncthreads();
        for (int s = 128; s; s >>= 1) {
            if (t < s) {
                float v2 = rv[t + s]; int i2 = ri[t + s];
                if (v2 > rv[t] || (v2 == rv[t] && i2 < ri[t])) { rv[t] = v2; ri[t] = i2; }
            }
            __syncthreads();
        }
        if (t == 0) {
            int bidx = ri[0];
            Mtop[bh * Uc + j] = bidx;
            vals[bidx] = -INFINITY;
        }
        __syncthreads();
    }
}

// ---------------------------------------------------------------------------
// QK scores: block per (b,h, l-chunk of 256). Writes RAW S directly into the
// selected rows of score_out.
// ---------------------------------------------------------------------------
__global__ __launch_bounds__(256) void qk_scores_kernel(
    const ushort* __restrict__ QK, const int* __restrict__ Mtop,
    float* __restrict__ score)
{
    const int bh = blockIdx.x >> 2;
    const int l0 = (blockIdx.x & 3) * 256;
    const int h = bh & (Hc - 1), b = bh >> 3;
    __shared__ int qpos[Uc];
    __shared__ float Qs[Uc][64];
    const int t = threadIdx.x;
    if (t < Uc) qpos[t] = Mtop[bh * Uc + t];
    __syncthreads();
    for (int i = t; i < Uc * 64; i += 256) {
        int j = i >> 6, d = i & 63;
        Qs[j][d] = bf2f(QK[(size_t)(b * Lc + qpos[j]) * 1024 + h * 64 + d]);
    }
    __syncthreads();

    const int l = l0 + t;
    const bf16x8* kr = reinterpret_cast<const bf16x8*>(
        QK + (size_t)(b * Lc + l) * 1024 + 512 + h * 64);
    float acc[Uc] = {};
    #pragma unroll
    for (int c = 0; c < 8; ++c) {
        bf16x8 kv = kr[c];
        float kf[8];
        #pragma unroll
        for (int e = 0; e < 8; ++e) kf[e] = bf2f((ushort)kv[e]);
        #pragma unroll
        for (int j = 0; j < Uc; ++j) {
            float s = 0.0f;
            #pragma unroll
            for (int e = 0; e < 8; ++e) s += Qs[j][c * 8 + e] * kf[e];
            acc[j] += s;
        }
    }
    #pragma unroll
    for (int j = 0; j < Uc; ++j)
        score[((size_t)(bh << 10) + qpos[j]) * Lc + l] = acc[j] * 0.125f;
}

// ---------------------------------------------------------------------------
// Fused attention output: block per (b,h), 256 threads (64 d x 4 part).
// Phase A: per-wave softmax stats (m, 1/Z) of the 35 raw rows (in score_out).
// Phase B: stage probs (exp(raw-m)/Z) -> LDS + write probs to score_out;
//          sweep V once accumulating PV[35][64] and the V column-mean.
// Phase C: write full ctx[b,:,h,:]: mean rows everywhere, PV rows on qpos.
// ---------------------------------------------------------------------------
__global__ __launch_bounds__(256) void attn_out_kernel(
    float* __restrict__ score, const float* __restrict__ V,
    const int* __restrict__ Mtop, ushort* __restrict__ ctx)
{
    const int bh = blockIdx.x;
    const int h = bh & (Hc - 1), b = bh >> 3;
    const int t = threadIdx.x;
    const int d = t & 63, part = t >> 6;

    __shared__ int qpos[Uc];
    __shared__ float mz[Uc][2];
    __shared__ float buf[4][Uc][64];   // prob chunk staging, then PV partials
    __shared__ float vmred[4][64];
    __shared__ float vmf[64];

    if (t < Uc) qpos[t] = Mtop[bh * Uc + t];
    __syncthreads();

    // Phase A: m_j, 1/Z_j (raw rows untouched)
    for (int j = part; j < Uc; j += 4) {
        const float* row = score + ((size_t)(bh << 10) + qpos[j]) * Lc;
        float v[16];
        float mx = -INFINITY;
        #pragma unroll
        for (int c = 0; c < 16; ++c) { v[c] = row[c * 64 + d]; mx = fmaxf(mx, v[c]); }
        #pragma unroll
        for (int off = 32; off; off >>= 1) mx = fmaxf(mx, __shfl_xor(mx, off, 64));
        float z = 0.0f;
        #pragma unroll
        for (int c = 0; c < 16; ++c) z += expf(v[c] - mx);
        #pragma unroll
        for (int off = 32; off; off >>= 1) z += __shfl_xor(z, off, 64);
        if (d == 0) { mz[j][0] = mx; mz[j][1] = 1.0f / z; }
    }
    __syncthreads();

    // Phase B: V sweep with on-the-fly probs
    float acc[Uc];
    #pragma unroll
    for (int j = 0; j < Uc; ++j) acc[j] = 0.0f;
    float vm = 0.0f;

    for (int c = 0; c < 4; ++c) {
        const int l0 = part * 256 + c * 64;
        #pragma unroll
        for (int j = 0; j < Uc; ++j) {
            size_t off = ((size_t)(bh << 10) + qpos[j]) * Lc + l0 + d;
            float p = expf(score[off] - mz[j][0]) * mz[j][1];
            buf[part][j][d] = p;
            score[off] = p;                 // final prob (never re-read here)
        }
        __syncthreads();
        #pragma unroll 4
        for (int li = 0; li < 64; ++li) {
            float v = V[((size_t)(b << 10) + l0 + li) * 512 + h * 64 + d];
            vm += v;
            #pragma unroll
            for (int j = 0; j < Uc; ++j) acc[j] += buf[part][j][li] * v;
        }
        __syncthreads();
    }

    // PV partials + mean partials into LDS
    #pragma unroll
    for (int j = 0; j < Uc; ++j) buf[part][j][d] = acc[j];
    vmred[part][d] = vm;
    __syncthreads();
    if (t < 64) vmf[t] = (vmred[0][t] + vmred[1][t] + vmred[2][t] + vmred[3][t]) * (1.0f / Lc);
    __syncthreads();

    // Phase C1: default (mean) rows for ALL l
    const int dcol = (t & 15) * 4;
    ushort4 vmu;
    vmu.x = f2bf(vmf[dcol + 0]); vmu.y = f2bf(vmf[dcol + 1]);
    vmu.z = f2bf(vmf[dcol + 2]); vmu.w = f2bf(vmf[dcol + 3]);
    for (int li = 0; li < 64; ++li) {
        int l = (t >> 4) + li * 16;
        *reinterpret_cast<ushort4*>(ctx + ((size_t)(b << 10) + l) * 512 + h * 64 + dcol) = vmu;
    }
    __syncthreads();   // drain default writes before overwriting selected rows

    // Phase C2: selected rows = PV
    for (int idx = t; idx < Uc * 64; idx += 256) {
        int j = idx >> 6, d2 = idx & 63;
        float s = buf[0][j][d2] + buf[1][j][d2] + buf[2][j][d2] + buf[3][j][d2];
        ctx[((size_t)(b << 10) + qpos[j]) * 512 + h * 64 + d2] = f2bf(s);
    }
}

// ---------------------------------------------------------------------------
// LayerNorm(a + b) * g + beta over DM=512. Thread handles elems 2t, 2t+1.
// A_BF/B_BF/OUT_BF select bf16 vs f32 for each tensor.
// ---------------------------------------------------------------------------
template<int A_BF, int B_BF, int OUT_BF>
__global__ __launch_bounds__(256) void ln_kernel(
    const void* __restrict__ a, const void* __restrict__ bsrc,
    const float* __restrict__ g, const float* __restrict__ beta,
    void* __restrict__ y)
{
    const int row = blockIdx.x;
    const int t = threadIdx.x;
    float a0, a1, b0, b1;
    if (A_BF) {
        uint32_t u = ((const uint32_t*)a)[(size_t)row * 256 + t];
        a0 = bf2f((ushort)(u & 0xffff)); a1 = bf2f((ushort)(u >> 16));
    } else {
        float2 f = ((const float2*)a)[(size_t)row * 256 + t];
        a0 = f.x; a1 = f.y;
    }
    if (B_BF) {
        uint32_t u = ((const uint32_t*)bsrc)[(size_t)row * 256 + t];
        b0 = bf2f((ushort)(u & 0xffff)); b1 = bf2f((ushort)(u >> 16));
    } else {
        float2 f = ((const float2*)bsrc)[(size_t)row * 256 + t];
        b0 = f.x; b1 = f.y;
    }
    float v0 = a0 + b0, v1 = a1 + b1;
    __shared__ float red[256];
    red[t] = v0 + v1; __syncthreads();
    for (int s = 128; s; s >>= 1) { if (t < s) red[t] += red[t + s]; __syncthreads(); }
    float mean = red[0] * (1.0f / DMc);
    __syncthreads();
    float d0 = v0 - mean, d1 = v1 - mean;
    red[t] = d0 * d0 + d1 * d1; __syncthreads();
    for (int s = 128; s; s >>= 1) { if (t < s) red[t] += red[t + s]; __syncthreads(); }
    float inv = rsqrtf(red[0] * (1.0f / DMc) + 1e-5f);
    float2 gv = ((const float2*)g)[t];
    float2 bt = ((const float2*)beta)[t];
    float o0 = gv.x * d0 * inv + bt.x;
    float o1 = gv.y * d1 * inv + bt.y;
    if (OUT_BF) {
        uint32_t u = (uint32_t)f2bf(o0) | ((uint32_t)f2bf(o1) << 16);
        ((uint32_t*)y)[(size_t)row * 256 + t] = u;
    } else {
        ((float2*)y)[(size_t)row * 256 + t] = make_float2(o0, o1);
    }
}

// ---------------------------------------------------------------------------
extern "C" void kernel_launch(void* const* d_in, const int* in_sizes, int n_in,
                              void* d_out, int out_size, void* d_ws, size_t ws_size,
                              hipStream_t stream)
{
    const float* x     = (const float*)d_in[0];
    const float* Wq    = (const float*)d_in[1];
    const float* bq    = (const float*)d_in[2];
    const float* Wk    = (const float*)d_in[3];
    const float* bk    = (const float*)d_in[4];
    const float* Wv    = (const float*)d_in[5];
    const float* bv    = (const float*)d_in[6];
    const float* Wo    = (const float*)d_in[7];
    const float* bo    = (const float*)d_in[8];
    const float* g1    = (const float*)d_in[9];
    const float* beta1 = (const float*)d_in[10];
    const float* W1    = (const float*)d_in[11];
    const float* bf1   = (const float*)d_in[12];
    const float* W2    = (const float*)d_in[13];
    const float* bf2   = (const float*)d_in[14];
    const float* g2    = (const float*)d_in[15];
    const float* beta2 = (const float*)d_in[16];
    const int* index_sample = (const int*)d_in[17];

    const size_t NTOK = (size_t)Bc * Lc;            // 16384
    const size_t QKV_SZ = NTOK * DMc;               // 8,388,608
    const size_t HID_SZ = NTOK * DHc;

    char* p = (char*)d_ws;
    auto alloc = [&](size_t bytes) { char* r = p; p += (bytes + 255) & ~(size_t)255; return r; };
    ushort* QKbf   = (ushort*)alloc(NTOK * 1024 * 2);   // [tok][Q(512)|K(512)]
    float*  V      = (float*) alloc(QKV_SZ * 4);
    ushort* hidden = (ushort*)alloc(HID_SZ * 2);
    ushort* xbf    = (ushort*)alloc(QKV_SZ * 2);
    ushort* ctxbf  = (ushort*)alloc(QKV_SZ * 2);
    ushort* x1bf   = (ushort*)alloc(QKV_SZ * 2);
    ushort* projbf = (ushort*)alloc(QKV_SZ * 2);
    float*  ffnf   = (float*) alloc(QKV_SZ * 4);
    ushort* Wqkvt  = (ushort*)alloc((size_t)1536 * 512 * 2);
    ushort* Wot    = (ushort*)alloc((size_t)512 * 512 * 2);
    ushort* W1t    = (ushort*)alloc((size_t)512 * 2048 * 2);
    ushort* W2t    = (ushort*)alloc((size_t)512 * 2048 * 2);
    float*  bcat   = (float*) alloc(1536 * 4);
    float*  Mbuf   = (float*) alloc((size_t)Bc * Hc * Lc * 4);
    int*    Mtop   = (int*)   alloc((size_t)Bc * Hc * 64 * 4);

    float* x2_out    = (float*)d_out;
    float* score_out = x2_out + QKV_SZ;

    dim3 blk(256);

    // default score fill + input prep
    fill_score_kernel<<<32768, blk, 0, stream>>>(score_out);
    prep_kernel<<<8192 + 4 * 256 + 2 * 1024 + 1, blk, 0, stream>>>(
        x, Wq, Wk, Wv, Wo, W1, W2, bq, bk, bv,
        xbf, Wqkvt, Wot, W1t, W2t, bcat);

    // fused QKV projection: Q,K -> bf16 QKbf, V -> f32
    gemm_mfma<3><<<12 * 128, blk, 0, stream>>>(
        xbf, Wqkvt, bcat, QKbf, V, (int)NTOK, 1536, 512, 12);

    // ProbSparse selection
    compute_M_kernel<<<(Bc * Hc * Lc) / 4, blk, 0, stream>>>(QKbf, index_sample, Mbuf);
    topk_kernel<<<Bc * Hc, blk, 0, stream>>>(Mbuf, Mtop);

    // raw scores into selected score rows, then fused softmax+PV+ctx
    qk_scores_kernel<<<Bc * Hc * 4, blk, 0, stream>>>(QKbf, Mtop, score_out);
    attn_out_kernel<<<Bc * Hc, blk, 0, stream>>>(score_out, V, Mtop, ctxbf);

    // output projection (bf16) + LN1 -> x1 (bf16 only)
    gemm_mfma<1><<<4 * 128, blk, 0, stream>>>(
        ctxbf, Wot, bo, projbf, nullptr, (int)NTOK, 512, 512, 4);
    ln_kernel<1, 0, 1><<<(int)NTOK, blk, 0, stream>>>(projbf, x, g1, beta1, x1bf);

    // FFN
    gemm_mfma<2><<<16 * 128, blk, 0, stream>>>(
        x1bf, W1t, bf1, hidden, nullptr, (int)NTOK, 2048, 512, 16);
    gemm_mfma<0><<<4 * 128, blk, 0, stream>>>(
        hidden, W2t, bf2, ffnf, nullptr, (int)NTOK, 512, 2048, 4);
    ln_kernel<0, 1, 0><<<(int)NTOK, blk, 0, stream>>>(ffnf, x1bf, g2, beta2, x2_out);
}